// Round 3
// baseline (244.392 us; speedup 1.0000x reference)
//
#include <hip/hip_runtime.h>
#include <hip/hip_fp16.h>

typedef _Float16 half8 __attribute__((ext_vector_type(8)));
typedef float float4v __attribute__((ext_vector_type(4)));

#define CHUNK 4096           // edges per hist/scatter block
#define BCAP  6144           // LDS staging capacity in k_bucket

// ========== phase 1: per-chunk LDS histogram (1024 thr) + misc init in block 0 ==========
__global__ void __launch_bounds__(1024) k_hist(
        const int* __restrict__ dst, int E, int* __restrict__ histT, int K, int NBS,
        const float* __restrict__ W3, const float* __restrict__ fcW,
        const float* __restrict__ b3, float* __restrict__ wfc,
        double* __restrict__ pool, int* __restrict__ rowptr, int* __restrict__ ctr, int N) {
    __shared__ int lh[256];
    int t = threadIdx.x, b = blockIdx.x;
    if (t < 256) lh[t] = 0;
    __syncthreads();
    int base = b * CHUNK;
    #pragma unroll
    for (int i = 0; i < 4; ++i) {
        int e = base + i * 1024 + t;
        if (e < E) atomicAdd(&lh[dst[e] >> 8], 1);   // LDS atomic
    }
    __syncthreads();
    if (t < K) histT[t * NBS + b] = lh[t];
    if (b == 0) {                                    // fold tiny init work here
        if (t < 256) pool[t] = 0.0;
        if (t == 0) { rowptr[N] = E; ctr[0] = 0; }
        if (t < 64) {                                // wfc[c]=(W3@fcW)[c]; wfc[64]=b3.fcW
            float v = 0.f;
            #pragma unroll 8
            for (int j = 0; j < 64; ++j) v += W3[t * 64 + j] * fcW[j];
            wfc[t] = v;
            float bb = b3[t] * fcW[t];
            for (int o = 32; o > 0; o >>= 1) bb += __shfl_down(bb, o, 64);
            if (t == 0) wfc[64] = bb;
        }
    }
}

// ========== phase 2: totals (tiled, redundant per block) + per-bucket chunk-offset scan ==========
__global__ void k_offsets(int* __restrict__ histT, int NB, int NBS, int K,
                          int* __restrict__ bucketBase, int* __restrict__ bucketCnt) {
    __shared__ int tt[256], sc[256];
    int k = blockIdx.x, t = threadIdx.x;
    int lane = t & 63, wid = t >> 6;
    tt[t] = 0;
    __syncthreads();
    // phase A: every block computes all bucket totals (coalesced: lanes stride cols)
    for (int row = wid; row < K; row += 4) {
        int s = 0;
        for (int b = lane; b < NB; b += 64) s += histT[row * NBS + b];
        for (int o = 32; o > 0; o >>= 1) s += __shfl_down(s, o, 64);
        if (lane == 0) tt[row] = s;
    }
    __syncthreads();
    // phase B: exclusive scan of totals -> this bucket's global base
    int v = tt[t];
    sc[t] = v;
    __syncthreads();
    for (int o = 1; o < 256; o <<= 1) {
        int u = (t >= o) ? sc[t - o] : 0;
        __syncthreads();
        sc[t] += u;
        __syncthreads();
    }
    int carry = sc[k] - tt[k];            // exclusive prefix at this block's bucket
    if (t == 0) { bucketBase[k] = carry; bucketCnt[k] = tt[k]; }
    // phase C: scan own row (chunk offsets within bucket)
    for (int tile = 0; tile < NB; tile += 256) {
        int b = tile + t;
        int hv = (b < NB) ? histT[k * NBS + b] : 0;
        __syncthreads();
        sc[t] = hv;
        __syncthreads();
        for (int o = 1; o < 256; o <<= 1) {
            int u = (t >= o) ? sc[t - o] : 0;
            __syncthreads();
            sc[t] += u;
            __syncthreads();
        }
        if (b < NB) histT[k * NBS + b] = carry + sc[t] - hv;
        carry += sc[255];
    }
}

// ========== phase 3: scatter edges into bucket-partitioned pairs (1024 thr) ==========
__global__ void __launch_bounds__(1024) k_scatter(
        const int* __restrict__ src, const int* __restrict__ dst, int E,
        const int* __restrict__ histT, int K, int NBS, unsigned* __restrict__ pairs) {
    __shared__ int cur[256];
    int t = threadIdx.x, b = blockIdx.x;
    if (t < K) cur[t] = histT[t * NBS + b];
    __syncthreads();
    int base = b * CHUNK;
    #pragma unroll
    for (int i = 0; i < 4; ++i) {
        int e = base + i * 1024 + t;
        if (e < E) {
            int d = dst[e];
            int pos = atomicAdd(&cur[d >> 8], 1);    // LDS atomic
            pairs[pos] = ((unsigned)(d & 255) << 16) | (unsigned)src[e];
        }
    }
}

// ========== phase 4: per-bucket exact CSR + rowptr/dinv/gx (1024 thr) ==========
__global__ void __launch_bounds__(1024) k_bucket(
        const unsigned* __restrict__ pairs, const int* __restrict__ bucketBase,
        const int* __restrict__ bucketCnt, const float* __restrict__ x,
        int* __restrict__ rowptr, float* __restrict__ dinv,
        __half* __restrict__ gx, unsigned short* __restrict__ col, int N) {
    __shared__ unsigned pl[BCAP];
    __shared__ unsigned short scol[BCAP];
    __shared__ int h[256], nb[256], cur[256];
    int k = blockIdx.x, t = threadIdx.x;
    int base = bucketBase[k], cnt = bucketCnt[k];
    bool stg = cnt <= BCAP;
    if (t < 256) h[t] = 0;
    if (stg) for (int i = t; i < cnt; i += 1024) pl[i] = pairs[base + i];
    __syncthreads();
    for (int i = t; i < cnt; i += 1024) {
        unsigned p = stg ? pl[i] : pairs[base + i];
        atomicAdd(&h[p >> 16], 1);                   // LDS atomic
    }
    __syncthreads();
    int d = (t < 256) ? h[t] : 0;
    if (t < 256) nb[t] = d;
    __syncthreads();
    for (int o = 1; o < 256; o <<= 1) {
        int v = (t < 256 && t >= o) ? nb[t - o] : 0;
        __syncthreads();
        if (t < 256) nb[t] += v;
        __syncthreads();
    }
    if (t < 256) {
        int excl = nb[t] - d;
        cur[t] = excl;
        int gid = (k << 8) + t;
        if (gid < N) {
            rowptr[gid] = base + excl;
            float di = rsqrtf((float)(d + 1));       // +1 self loop
            dinv[gid] = di;
            #pragma unroll
            for (int q = 0; q < 16; ++q)
                gx[gid * 16 + q] = __float2half(q < 10 ? x[gid * 10 + q] * di : 0.f);
        }
    }
    __syncthreads();
    // placement: scatter into LDS, then stream out coalesced
    for (int i = t; i < cnt; i += 1024) {
        unsigned p = stg ? pl[i] : pairs[base + i];
        int j = p >> 16;
        int pos = atomicAdd(&cur[j], 1);             // LDS atomic
        if (stg) scol[pos] = (unsigned short)(p & 0xFFFFu);
        else     col[base + pos] = (unsigned short)(p & 0xFFFFu);
    }
    __syncthreads();
    if (stg) for (int i = t; i < cnt; i += 1024) col[base + i] = scol[i];
}

// ========== layer 1: gather gx16 (1.6MB, L2-resident), 16 lanes/node ==========
// output: interleaved g1 (128B/node): lane f's 4 output feats at byte offset f*8
__global__ void k_L1(const __half* __restrict__ gx, const float* __restrict__ W1,
                     const float* __restrict__ b1, const int* __restrict__ rowptr,
                     const unsigned short* __restrict__ col, const float* __restrict__ dinv,
                     __half* __restrict__ g1, int N) {
    __shared__ float sW[10 * 64];
    __shared__ float sB[64];
    int t = threadIdx.x;
    for (int i = t; i < 640; i += 256) sW[i] = W1[i];
    if (t < 64) sB[t] = b1[t];
    __syncthreads();
    int node = blockIdx.x * 16 + (t >> 4);
    int f = t & 15;
    bool live = node < N;
    bool act = live && (f < 10);
    const char* gp = (const char*)gx;
    unsigned fo = (unsigned)(f << 1);
    float di = live ? dinv[node] : 0.f;
    float a = act ? __half2float(*(const __half*)(gp + ((unsigned)node << 5) + fo)) : 0.f;
    int s0 = 0, s1 = 0;
    if (live) { s0 = rowptr[node]; s1 = rowptr[node + 1]; }
    int e = s0;
    for (; e + 4 <= s1; e += 4) {
        unsigned j0 = col[e], j1 = col[e + 1], j2 = col[e + 2], j3 = col[e + 3];
        float v0 = 0.f, v1 = 0.f, v2 = 0.f, v3 = 0.f;
        if (act) {
            v0 = __half2float(*(const __half*)(gp + (j0 << 5) + fo));
            v1 = __half2float(*(const __half*)(gp + (j1 << 5) + fo));
            v2 = __half2float(*(const __half*)(gp + (j2 << 5) + fo));
            v3 = __half2float(*(const __half*)(gp + (j3 << 5) + fo));
        }
        a += (v0 + v1) + (v2 + v3);
    }
    for (; e < s1; ++e) {
        unsigned j = col[e];
        if (act) a += __half2float(*(const __half*)(gp + (j << 5) + fo));
    }
    a *= di;                                   // P_i(x)[f], f<10
    int gb = t & 48;
    float c0 = 0.f, c1 = 0.f, c2 = 0.f, c3 = 0.f;
    int c4 = 4 * f;
    #pragma unroll
    for (int k = 0; k < 10; ++k) {
        float ak = __shfl(a, gb + k, 64);
        c0 += ak * sW[k * 64 + c4];
        c1 += ak * sW[k * 64 + c4 + 1];
        c2 += ak * sW[k * 64 + c4 + 2];
        c3 += ak * sW[k * 64 + c4 + 3];
    }
    if (!live) return;
    float h0 = di * fmaxf(c0 + sB[c4], 0.f);
    float h1 = di * fmaxf(c1 + sB[c4 + 1], 0.f);
    float h2 = di * fmaxf(c2 + sB[c4 + 2], 0.f);
    float h3 = di * fmaxf(c3 + sB[c4 + 3], 0.f);
    union { __half h[4]; uint2 u; } pk;
    pk.h[0] = __float2half(h0); pk.h[1] = __float2half(h1);
    pk.h[2] = __float2half(h2); pk.h[3] = __float2half(h3);
    *(uint2*)((char*)g1 + ((unsigned)node << 7) + (unsigned)(f << 3)) = pk.u;
}

// ========== layer 2 (merged): single gather over g1 (6.4MB) + MFMA epilogue -> tvec ==========
__global__ void __launch_bounds__(256) k_L2(
        const __half* __restrict__ g1,
        const float* __restrict__ W2, const float* __restrict__ b2,
        const float* __restrict__ wfcv, const int* __restrict__ rowptr,
        const unsigned short* __restrict__ col, const float* __restrict__ dinv,
        float* __restrict__ tvec, int N) {
    __shared__ __align__(16) __half At[16 * 72];   // 16 nodes x 64 feats, stride 72
    __shared__ float sRed[4][16];
    __shared__ float sDi[16];
    int t = threadIdx.x;
    int lane = t & 63, wid = t >> 6;
    int m = lane & 15, quad = lane >> 4;

    // B fragments: W2 column cg, fp16 hi/lo split (registers, overlaps gather)
    int cg = (wid << 4) + m;
    half8 H0, L0, H1, L1;
    #pragma unroll
    for (int j = 0; j < 8; ++j) {
        float w0 = W2[(quad * 8 + j) * 64 + cg];
        _Float16 h0 = (_Float16)w0;
        H0[j] = h0; L0[j] = (_Float16)(w0 - (float)h0);
        float w1 = W2[(32 + quad * 8 + j) * 64 + cg];
        _Float16 h1 = (_Float16)w1;
        H1[j] = h1; L1[j] = (_Float16)(w1 - (float)h1);
    }
    float bc = b2[cg], wf = wfcv[cg];

    // gather g1: 16 nodes/block, 16 lanes/node, 4 feats (uint2, 8B) per lane
    int nl = t >> 4, f4 = t & 15;
    int node = blockIdx.x * 16 + nl;
    bool live = node < N;
    float di = live ? dinv[node] : 0.f;
    float ax = 0.f, ay = 0.f, az = 0.f, aw = 0.f;
    if (live) {
        const char* gp = (const char*)g1;
        unsigned fo = (unsigned)(f4 << 3);
        uint2 us = *(const uint2*)(gp + ((unsigned)node << 7) + fo);
        float2 slo = __half22float2(*(__half2*)&us.x);
        float2 shi = __half22float2(*(__half2*)&us.y);
        ax = slo.x; ay = slo.y; az = shi.x; aw = shi.y;
        int s0 = rowptr[node], s1 = rowptr[node + 1];
        int e = s0;
        for (; e + 8 <= s1; e += 8) {
            unsigned j0 = col[e],     j1 = col[e + 1], j2 = col[e + 2], j3 = col[e + 3];
            unsigned j4 = col[e + 4], j5 = col[e + 5], j6 = col[e + 6], j7 = col[e + 7];
            uint2 u0 = *(const uint2*)(gp + (j0 << 7) + fo);
            uint2 u1 = *(const uint2*)(gp + (j1 << 7) + fo);
            uint2 u2 = *(const uint2*)(gp + (j2 << 7) + fo);
            uint2 u3 = *(const uint2*)(gp + (j3 << 7) + fo);
            uint2 u4 = *(const uint2*)(gp + (j4 << 7) + fo);
            uint2 u5 = *(const uint2*)(gp + (j5 << 7) + fo);
            uint2 u6 = *(const uint2*)(gp + (j6 << 7) + fo);
            uint2 u7 = *(const uint2*)(gp + (j7 << 7) + fo);
            float2 a0 = __half22float2(*(__half2*)&u0.x), b0 = __half22float2(*(__half2*)&u0.y);
            float2 a1 = __half22float2(*(__half2*)&u1.x), b1v = __half22float2(*(__half2*)&u1.y);
            float2 a2 = __half22float2(*(__half2*)&u2.x), b2v = __half22float2(*(__half2*)&u2.y);
            float2 a3 = __half22float2(*(__half2*)&u3.x), b3v = __half22float2(*(__half2*)&u3.y);
            float2 a4 = __half22float2(*(__half2*)&u4.x), b4 = __half22float2(*(__half2*)&u4.y);
            float2 a5 = __half22float2(*(__half2*)&u5.x), b5 = __half22float2(*(__half2*)&u5.y);
            float2 a6 = __half22float2(*(__half2*)&u6.x), b6 = __half22float2(*(__half2*)&u6.y);
            float2 a7 = __half22float2(*(__half2*)&u7.x), b7 = __half22float2(*(__half2*)&u7.y);
            ax += ((a0.x + a1.x) + (a2.x + a3.x)) + ((a4.x + a5.x) + (a6.x + a7.x));
            ay += ((a0.y + a1.y) + (a2.y + a3.y)) + ((a4.y + a5.y) + (a6.y + a7.y));
            az += ((b0.x + b1v.x) + (b2v.x + b3v.x)) + ((b4.x + b5.x) + (b6.x + b7.x));
            aw += ((b0.y + b1v.y) + (b2v.y + b3v.y)) + ((b4.y + b5.y) + (b6.y + b7.y));
        }
        for (; e < s1; ++e) {
            uint2 u0 = *(const uint2*)(gp + ((unsigned)col[e] << 7) + fo);
            float2 a0 = __half22float2(*(__half2*)&u0.x), b0 = __half22float2(*(__half2*)&u0.y);
            ax += a0.x; ay += a0.y; az += b0.x; aw += b0.y;
        }
    }
    union { __half h[4]; uint2 u; } pk;
    pk.h[0] = __float2half(ax * di); pk.h[1] = __float2half(ay * di);
    pk.h[2] = __float2half(az * di); pk.h[3] = __float2half(aw * di);
    *(uint2*)&At[nl * 72 + 4 * f4] = pk.u;    // feats 4*f4 .. 4*f4+3 of node nl
    if (f4 == 0) sDi[nl] = di;
    __syncthreads();

    // MFMA: D[m=node][n=col] = A(16x64) @ W2(64x64); this wave: cols 16*wid..
    half8 A0 = *reinterpret_cast<const half8*>(&At[m * 72 + quad * 8]);
    half8 A1 = *reinterpret_cast<const half8*>(&At[m * 72 + 32 + quad * 8]);
    float4v C = {0.f, 0.f, 0.f, 0.f};
    C = __builtin_amdgcn_mfma_f32_16x16x32_f16(A0, H0, C, 0, 0, 0);
    C = __builtin_amdgcn_mfma_f32_16x16x32_f16(A0, L0, C, 0, 0, 0);
    C = __builtin_amdgcn_mfma_f32_16x16x32_f16(A1, H1, C, 0, 0, 0);
    C = __builtin_amdgcn_mfma_f32_16x16x32_f16(A1, L1, C, 0, 0, 0);

    // epilogue: relu(C+b2)*wfc, reduce over cols -> per-node scalar
    float v0 = fmaxf(C[0] + bc, 0.f) * wf;
    float v1 = fmaxf(C[1] + bc, 0.f) * wf;
    float v2 = fmaxf(C[2] + bc, 0.f) * wf;
    float v3 = fmaxf(C[3] + bc, 0.f) * wf;
    #pragma unroll
    for (int o = 1; o < 16; o <<= 1) {
        v0 += __shfl_xor(v0, o, 64);
        v1 += __shfl_xor(v1, o, 64);
        v2 += __shfl_xor(v2, o, 64);
        v3 += __shfl_xor(v3, o, 64);
    }
    if (m == 0) {
        sRed[wid][quad * 4 + 0] = v0;
        sRed[wid][quad * 4 + 1] = v1;
        sRed[wid][quad * 4 + 2] = v2;
        sRed[wid][quad * 4 + 3] = v3;
    }
    __syncthreads();
    if (t < 16) {
        int ng = blockIdx.x * 16 + t;
        if (ng < N) {
            float tt = sRed[0][t] + sRed[1][t] + sRed[2][t] + sRed[3][t];
            tvec[ng] = sDi[t] * tt;            // t_j = dinv_j * (h2_j . wfc)
        }
    }
}

// ========== layer 3: scalar gather over tvec (200KB) + mean-pool + last-block finalize ==========
__global__ void __launch_bounds__(256) k_agg3(
        const float* __restrict__ tvec, const int* __restrict__ rowptr,
        const unsigned short* __restrict__ col, const float* __restrict__ dinv,
        double* __restrict__ pool, int* __restrict__ ctr,
        const float* __restrict__ wfc, const float* __restrict__ fcb,
        float* __restrict__ out, double invN, int N) {
    int tid = blockIdx.x * 256 + threadIdx.x;
    int node = tid >> 4, lane = tid & 15;
    if (node < N) {
        int s0 = rowptr[node], s1 = rowptr[node + 1];
        float s = 0.f;
        for (int e = s0 + lane; e < s1; e += 16) s += tvec[col[e]];
        #pragma unroll
        for (int o = 1; o < 16; o <<= 1) s += __shfl_xor(s, o, 64);
        if (lane == 0) {
            double contrib = (double)(dinv[node] * (tvec[node] + s));
            atomicAdd(&pool[node & 255], contrib);
        }
    }
    // last-block-done finalization (replaces k_final)
    __shared__ int isLast;
    __syncthreads();
    if (threadIdx.x == 0) {
        __threadfence();
        isLast = (atomicAdd(ctr, 1) == (int)gridDim.x - 1) ? 1 : 0;
    }
    __syncthreads();
    if (isLast) {
        __threadfence();
        __shared__ double s[256];
        int t = threadIdx.x;
        s[t] = pool[t];
        __syncthreads();
        for (int o = 128; o > 0; o >>= 1) {
            if (t < o) s[t] += s[t + o];
            __syncthreads();
        }
        if (t == 0) out[0] = (float)(s[0] * invN) + wfc[64] + fcb[0];
    }
}

extern "C" void kernel_launch(void* const* d_in, const int* in_sizes, int n_in,
                              void* d_out, int out_size, void* d_ws, size_t ws_size,
                              hipStream_t stream) {
    const float* x   = (const float*)d_in[0];
    const int*   ei  = (const int*)d_in[1];
    const float* W1  = (const float*)d_in[2];
    const float* b1  = (const float*)d_in[3];
    const float* W2  = (const float*)d_in[4];
    const float* b2  = (const float*)d_in[5];
    const float* W3  = (const float*)d_in[6];
    const float* b3  = (const float*)d_in[7];
    const float* fcW = (const float*)d_in[8];
    const float* fcb = (const float*)d_in[9];

    const int N = in_sizes[0] / 10;
    const int E = in_sizes[1] / 2;
    const int* src = ei;
    const int* dst = ei + E;

    const int K   = (N + 255) >> 8;            // buckets of 256 nodes (196)
    const int NB  = (E + CHUNK - 1) / CHUNK;   // chunks (196)
    const int NBS = NB | 1;                    // odd stride

    // ---- workspace carve-up (256B aligned) ----
    char* w = (char*)d_ws;
    size_t off = 0;
    auto alloc = [&](size_t bytes) -> void* {
        void* p = w + off;
        off += (bytes + 255) & ~(size_t)255;
        return p;
    };
    int*      histT      = (int*)alloc((size_t)K * NBS * 4);
    int*      bucketBase = (int*)alloc((size_t)K * 4);
    int*      bucketCnt  = (int*)alloc((size_t)K * 4);
    unsigned* pairs      = (unsigned*)alloc((size_t)E * 4);
    unsigned short* col  = (unsigned short*)alloc((size_t)E * 2);
    int*      rowptr     = (int*)alloc((size_t)(N + 1) * 4);
    float*    dinv       = (float*)alloc((size_t)N * 4);
    double*   pool       = (double*)alloc(256 * 8);
    float*    wfc        = (float*)alloc(65 * 4);
    float*    tvec       = (float*)alloc((size_t)N * 4);
    int*      ctr        = (int*)alloc(4);
    __half*   gx         = (__half*)alloc((size_t)N * 16 * 2);
    __half*   g1         = (__half*)alloc((size_t)N * 64 * 2);   // interleaved h1, 128B/node
    (void)ws_size; (void)n_in; (void)out_size;

    const int nbNode16 = (N + 15) / 16;

    // ---- atomic-free CSR build (counting sort, LDS atomics only) ----
    k_hist   <<<NB, 1024, 0, stream>>>(dst, E, histT, K, NBS,
                                       W3, fcW, b3, wfc, pool, rowptr, ctr, N);
    k_offsets<<<K, 256, 0, stream>>>(histT, NB, NBS, K, bucketBase, bucketCnt);
    k_scatter<<<NB, 1024, 0, stream>>>(src, dst, E, histT, K, NBS, pairs);
    k_bucket <<<K, 1024, 0, stream>>>(pairs, bucketBase, bucketCnt, x,
                                      rowptr, dinv, gx, col, N);

    // ---- fused layers ----
    k_L1 <<<nbNode16, 256, 0, stream>>>(gx, W1, b1, rowptr, col, dinv, g1, N);
    k_L2 <<<nbNode16, 256, 0, stream>>>(g1, W2, b2, wfc, rowptr, col, dinv, tvec, N);
    k_agg3<<<nbNode16, 256, 0, stream>>>(tvec, rowptr, col, dinv, pool, ctr,
                                         wfc, fcb, (float*)d_out, 1.0 / (double)N, N);
}

// Round 4
// 185.785 us; speedup vs baseline: 1.3155x; 1.3155x over previous
//
#include <hip/hip_runtime.h>
#include <hip/hip_fp16.h>

typedef _Float16 half8 __attribute__((ext_vector_type(8)));
typedef float float4v __attribute__((ext_vector_type(4)));

#define CHUNK 2048           // edges per hist/scatter block
#define BCAP  6144           // LDS staging capacity in k_bucket

// ========== phase 1: per-chunk LDS histogram (1024 thr) + misc init in block 0 ==========
__global__ void __launch_bounds__(1024) k_hist(
        const int* __restrict__ dst, int E, int* __restrict__ histT, int K, int NBS,
        const float* __restrict__ W3, const float* __restrict__ fcW,
        const float* __restrict__ b3, float* __restrict__ wfc,
        double* __restrict__ pool, int* __restrict__ rowptr,
        float* __restrict__ q, int N) {
    __shared__ int lh[256];
    int t = threadIdx.x, b = blockIdx.x;
    if (t < 256) lh[t] = 0;
    __syncthreads();
    int qi = b * 1024 + t;                           // NB*1024 >= N: zero q here
    if (qi < N) q[qi] = 0.f;
    int base = b * CHUNK;
    #pragma unroll
    for (int i = 0; i < 2; ++i) {
        int e = base + i * 1024 + t;
        if (e < E) atomicAdd(&lh[dst[e] >> 8], 1);   // LDS atomic
    }
    __syncthreads();
    if (t < K) histT[t * NBS + b] = lh[t];
    if (b == 0) {                                    // fold tiny init work here
        if (t < 256) pool[t] = 0.0;
        if (t == 0) rowptr[N] = E;
        if (t < 64) {                                // wfc[c]=(W3@fcW)[c]; wfc[64]=b3.fcW
            float v = 0.f;
            #pragma unroll 8
            for (int j = 0; j < 64; ++j) v += W3[t * 64 + j] * fcW[j];
            wfc[t] = v;
            float bb = b3[t] * fcW[t];
            for (int o = 32; o > 0; o >>= 1) bb += __shfl_down(bb, o, 64);
            if (t == 0) wfc[64] = bb;
        }
    }
}

// ========== phase 2a: per-bucket totals (one wave per bucket) ==========
__global__ void k_tot(const int* __restrict__ histT, int NB, int NBS, int* __restrict__ tot) {
    int k = blockIdx.x, t = threadIdx.x;
    int s = 0;
    for (int b = t; b < NB; b += 64) s += histT[k * NBS + b];
    for (int o = 32; o > 0; o >>= 1) s += __shfl_down(s, o, 64);
    if (t == 0) tot[k] = s;
}

// ========== phase 2b: per-bucket chunk-offset scan; each block re-derives its base ==========
__global__ void k_offsets(int* __restrict__ histT, int NB, int NBS, int K,
                          const int* __restrict__ tot,
                          int* __restrict__ bucketBase, int* __restrict__ bucketCnt) {
    __shared__ int sc[256], tt[256];
    int k = blockIdx.x, t = threadIdx.x;
    int v = (t < K) ? tot[t] : 0;
    sc[t] = v; tt[t] = v;
    __syncthreads();
    for (int o = 1; o < 256; o <<= 1) {
        int u = (t >= o) ? sc[t - o] : 0;
        __syncthreads();
        sc[t] += u;
        __syncthreads();
    }
    int carry = sc[k] - tt[k];            // exclusive prefix at this block's bucket
    if (t == 0) { bucketBase[k] = carry; bucketCnt[k] = tt[k]; }
    for (int tile = 0; tile < NB; tile += 256) {
        int b = tile + t;
        int hv = (b < NB) ? histT[k * NBS + b] : 0;
        __syncthreads();
        sc[t] = hv;
        __syncthreads();
        for (int o = 1; o < 256; o <<= 1) {
            int u = (t >= o) ? sc[t - o] : 0;
            __syncthreads();
            sc[t] += u;
            __syncthreads();
        }
        if (b < NB) histT[k * NBS + b] = carry + sc[t] - hv;
        carry += sc[255];
    }
}

// ========== phase 3: scatter edges into bucket-partitioned pairs (1024 thr) ==========
__global__ void __launch_bounds__(1024) k_scatter(
        const int* __restrict__ src, const int* __restrict__ dst, int E,
        const int* __restrict__ histT, int K, int NBS, unsigned* __restrict__ pairs) {
    __shared__ int cur[256];
    int t = threadIdx.x, b = blockIdx.x;
    if (t < K) cur[t] = histT[t * NBS + b];
    __syncthreads();
    int base = b * CHUNK;
    #pragma unroll
    for (int i = 0; i < 2; ++i) {
        int e = base + i * 1024 + t;
        if (e < E) {
            int d = dst[e];
            int pos = atomicAdd(&cur[d >> 8], 1);    // LDS atomic
            pairs[pos] = ((unsigned)(d & 255) << 16) | (unsigned)src[e];
        }
    }
}

// ========== phase 4: per-bucket exact CSR + rowptr/dinv/gx + q scatter (1024 thr) ==========
__global__ void __launch_bounds__(1024) k_bucket(
        const unsigned* __restrict__ pairs, const int* __restrict__ bucketBase,
        const int* __restrict__ bucketCnt, const float* __restrict__ x,
        int* __restrict__ rowptr, float* __restrict__ dinv,
        __half* __restrict__ gx, unsigned short* __restrict__ col,
        float* __restrict__ q, int N) {
    __shared__ unsigned pl[BCAP];
    __shared__ int h[256], nb[256], cur[256];
    __shared__ float sdi[256];
    int k = blockIdx.x, t = threadIdx.x;
    int base = bucketBase[k], cnt = bucketCnt[k];
    bool stg = cnt <= BCAP;
    if (t < 256) { h[t] = 0; sdi[t] = 0.f; }
    if (stg) for (int i = t; i < cnt; i += 1024) pl[i] = pairs[base + i];
    __syncthreads();
    for (int i = t; i < cnt; i += 1024) {
        unsigned p = stg ? pl[i] : pairs[base + i];
        atomicAdd(&h[p >> 16], 1);                   // LDS atomic
    }
    __syncthreads();
    int d = (t < 256) ? h[t] : 0;
    if (t < 256) nb[t] = d;
    __syncthreads();
    for (int o = 1; o < 256; o <<= 1) {
        int v = (t < 256 && t >= o) ? nb[t - o] : 0;
        __syncthreads();
        if (t < 256) nb[t] += v;
        __syncthreads();
    }
    if (t < 256) {
        int excl = nb[t] - d;
        cur[t] = excl;
        int gid = (k << 8) + t;
        if (gid < N) {
            rowptr[gid] = base + excl;
            float di = rsqrtf((float)(d + 1));       // +1 self loop
            dinv[gid] = di;
            sdi[t] = di;
            #pragma unroll
            for (int q2 = 0; q2 < 16; ++q2)
                gx[gid * 16 + q2] = __float2half(q2 < 10 ? x[gid * 10 + q2] * di : 0.f);
        }
    }
    __syncthreads();
    for (int i = t; i < cnt; i += 1024) {
        unsigned p = stg ? pl[i] : pairs[base + i];
        int j = p >> 16;
        int pos = atomicAdd(&cur[j], 1);             // LDS atomic
        col[base + pos] = (unsigned short)(p & 0xFFFFu);
        atomicAdd(&q[p & 0xFFFFu], sdi[j]);          // q[src] += dinv[dst]
    }
}

// ========== layer 1: gather gx16 (1.6MB, L2-resident), 16 lanes/node ==========
// output: interleaved g1 (128B/node): lane f's 4 output feats at byte offset f*8
__global__ void k_L1(const __half* __restrict__ gx, const float* __restrict__ W1,
                     const float* __restrict__ b1, const int* __restrict__ rowptr,
                     const unsigned short* __restrict__ col, const float* __restrict__ dinv,
                     __half* __restrict__ g1, int N) {
    __shared__ float sW[10 * 64];
    __shared__ float sB[64];
    int t = threadIdx.x;
    for (int i = t; i < 640; i += 256) sW[i] = W1[i];
    if (t < 64) sB[t] = b1[t];
    __syncthreads();
    int node = blockIdx.x * 16 + (t >> 4);
    int f = t & 15;
    bool live = node < N;
    bool act = live && (f < 10);
    const char* gp = (const char*)gx;
    unsigned fo = (unsigned)(f << 1);
    float di = live ? dinv[node] : 0.f;
    float a = act ? __half2float(*(const __half*)(gp + ((unsigned)node << 5) + fo)) : 0.f;
    int s0 = 0, s1 = 0;
    if (live) { s0 = rowptr[node]; s1 = rowptr[node + 1]; }
    int e = s0;
    for (; e + 4 <= s1; e += 4) {
        unsigned j0 = col[e], j1 = col[e + 1], j2 = col[e + 2], j3 = col[e + 3];
        float v0 = 0.f, v1 = 0.f, v2 = 0.f, v3 = 0.f;
        if (act) {
            v0 = __half2float(*(const __half*)(gp + (j0 << 5) + fo));
            v1 = __half2float(*(const __half*)(gp + (j1 << 5) + fo));
            v2 = __half2float(*(const __half*)(gp + (j2 << 5) + fo));
            v3 = __half2float(*(const __half*)(gp + (j3 << 5) + fo));
        }
        a += (v0 + v1) + (v2 + v3);
    }
    for (; e < s1; ++e) {
        unsigned j = col[e];
        if (act) a += __half2float(*(const __half*)(gp + (j << 5) + fo));
    }
    a *= di;                                   // P_i(x)[f], f<10
    int gb = t & 48;
    float c0 = 0.f, c1 = 0.f, c2 = 0.f, c3 = 0.f;
    int c4 = 4 * f;
    #pragma unroll
    for (int k = 0; k < 10; ++k) {
        float ak = __shfl(a, gb + k, 64);
        c0 += ak * sW[k * 64 + c4];
        c1 += ak * sW[k * 64 + c4 + 1];
        c2 += ak * sW[k * 64 + c4 + 2];
        c3 += ak * sW[k * 64 + c4 + 3];
    }
    if (!live) return;
    float h0 = di * fmaxf(c0 + sB[c4], 0.f);
    float h1 = di * fmaxf(c1 + sB[c4 + 1], 0.f);
    float h2 = di * fmaxf(c2 + sB[c4 + 2], 0.f);
    float h3 = di * fmaxf(c3 + sB[c4 + 3], 0.f);
    union { __half h[4]; uint2 u; } pk;
    pk.h[0] = __float2half(h0); pk.h[1] = __float2half(h1);
    pk.h[2] = __float2half(h2); pk.h[3] = __float2half(h3);
    *(uint2*)((char*)g1 + ((unsigned)node << 7) + (unsigned)(f << 3)) = pk.u;
}

// ========== layer 2 (merged): gather g1 (6.4MB) + MFMA + fold layer3 contribution ==========
__global__ void __launch_bounds__(256) k_L2(
        const __half* __restrict__ g1,
        const float* __restrict__ W2, const float* __restrict__ b2,
        const float* __restrict__ wfcv, const int* __restrict__ rowptr,
        const unsigned short* __restrict__ col, const float* __restrict__ dinv,
        const float* __restrict__ q, double* __restrict__ pool, int N) {
    __shared__ __align__(16) __half At[16 * 72];   // 16 nodes x 64 feats, stride 72
    __shared__ float sRed[4][16];
    __shared__ float sDi[16];
    int t = threadIdx.x;
    int lane = t & 63, wid = t >> 6;
    int m = lane & 15, quad = lane >> 4;

    // B fragments: W2 column cg, fp16 hi/lo split (registers, overlaps gather)
    int cg = (wid << 4) + m;
    half8 H0, L0, H1, L1;
    #pragma unroll
    for (int j = 0; j < 8; ++j) {
        float w0 = W2[(quad * 8 + j) * 64 + cg];
        _Float16 h0 = (_Float16)w0;
        H0[j] = h0; L0[j] = (_Float16)(w0 - (float)h0);
        float w1 = W2[(32 + quad * 8 + j) * 64 + cg];
        _Float16 h1 = (_Float16)w1;
        H1[j] = h1; L1[j] = (_Float16)(w1 - (float)h1);
    }
    float bc = b2[cg], wf = wfcv[cg];

    // gather g1: 16 nodes/block, 16 lanes/node, 4 feats (uint2, 8B) per lane
    int nl = t >> 4, f4 = t & 15;
    int node = blockIdx.x * 16 + nl;
    bool live = node < N;
    float di = live ? dinv[node] : 0.f;
    float ax = 0.f, ay = 0.f, az = 0.f, aw = 0.f;
    if (live) {
        const char* gp = (const char*)g1;
        unsigned fo = (unsigned)(f4 << 3);
        uint2 us = *(const uint2*)(gp + ((unsigned)node << 7) + fo);
        float2 slo = __half22float2(*(__half2*)&us.x);
        float2 shi = __half22float2(*(__half2*)&us.y);
        ax = slo.x; ay = slo.y; az = shi.x; aw = shi.y;
        int s0 = rowptr[node], s1 = rowptr[node + 1];
        int e = s0;
        for (; e + 8 <= s1; e += 8) {
            unsigned j0 = col[e],     j1 = col[e + 1], j2 = col[e + 2], j3 = col[e + 3];
            unsigned j4 = col[e + 4], j5 = col[e + 5], j6 = col[e + 6], j7 = col[e + 7];
            uint2 u0 = *(const uint2*)(gp + (j0 << 7) + fo);
            uint2 u1 = *(const uint2*)(gp + (j1 << 7) + fo);
            uint2 u2 = *(const uint2*)(gp + (j2 << 7) + fo);
            uint2 u3 = *(const uint2*)(gp + (j3 << 7) + fo);
            uint2 u4 = *(const uint2*)(gp + (j4 << 7) + fo);
            uint2 u5 = *(const uint2*)(gp + (j5 << 7) + fo);
            uint2 u6 = *(const uint2*)(gp + (j6 << 7) + fo);
            uint2 u7 = *(const uint2*)(gp + (j7 << 7) + fo);
            float2 a0 = __half22float2(*(__half2*)&u0.x), b0 = __half22float2(*(__half2*)&u0.y);
            float2 a1 = __half22float2(*(__half2*)&u1.x), b1v = __half22float2(*(__half2*)&u1.y);
            float2 a2 = __half22float2(*(__half2*)&u2.x), b2v = __half22float2(*(__half2*)&u2.y);
            float2 a3 = __half22float2(*(__half2*)&u3.x), b3v = __half22float2(*(__half2*)&u3.y);
            float2 a4 = __half22float2(*(__half2*)&u4.x), b4 = __half22float2(*(__half2*)&u4.y);
            float2 a5 = __half22float2(*(__half2*)&u5.x), b5 = __half22float2(*(__half2*)&u5.y);
            float2 a6 = __half22float2(*(__half2*)&u6.x), b6 = __half22float2(*(__half2*)&u6.y);
            float2 a7 = __half22float2(*(__half2*)&u7.x), b7 = __half22float2(*(__half2*)&u7.y);
            ax += ((a0.x + a1.x) + (a2.x + a3.x)) + ((a4.x + a5.x) + (a6.x + a7.x));
            ay += ((a0.y + a1.y) + (a2.y + a3.y)) + ((a4.y + a5.y) + (a6.y + a7.y));
            az += ((b0.x + b1v.x) + (b2v.x + b3v.x)) + ((b4.x + b5.x) + (b6.x + b7.x));
            aw += ((b0.y + b1v.y) + (b2v.y + b3v.y)) + ((b4.y + b5.y) + (b6.y + b7.y));
        }
        for (; e < s1; ++e) {
            uint2 u0 = *(const uint2*)(gp + ((unsigned)col[e] << 7) + fo);
            float2 a0 = __half22float2(*(__half2*)&u0.x), b0 = __half22float2(*(__half2*)&u0.y);
            ax += a0.x; ay += a0.y; az += b0.x; aw += b0.y;
        }
    }
    union { __half h[4]; uint2 u; } pk;
    pk.h[0] = __float2half(ax * di); pk.h[1] = __float2half(ay * di);
    pk.h[2] = __float2half(az * di); pk.h[3] = __float2half(aw * di);
    *(uint2*)&At[nl * 72 + 4 * f4] = pk.u;    // feats 4*f4 .. 4*f4+3 of node nl
    if (f4 == 0) sDi[nl] = di;
    __syncthreads();

    // MFMA: D[m=node][n=col] = A(16x64) @ W2(64x64); this wave: cols 16*wid..
    half8 A0 = *reinterpret_cast<const half8*>(&At[m * 72 + quad * 8]);
    half8 A1 = *reinterpret_cast<const half8*>(&At[m * 72 + 32 + quad * 8]);
    float4v C = {0.f, 0.f, 0.f, 0.f};
    C = __builtin_amdgcn_mfma_f32_16x16x32_f16(A0, H0, C, 0, 0, 0);
    C = __builtin_amdgcn_mfma_f32_16x16x32_f16(A0, L0, C, 0, 0, 0);
    C = __builtin_amdgcn_mfma_f32_16x16x32_f16(A1, H1, C, 0, 0, 0);
    C = __builtin_amdgcn_mfma_f32_16x16x32_f16(A1, L1, C, 0, 0, 0);

    // epilogue: relu(C+b2)*wfc, reduce over cols -> u_j; fold layer-3 via q
    float v0 = fmaxf(C[0] + bc, 0.f) * wf;
    float v1 = fmaxf(C[1] + bc, 0.f) * wf;
    float v2 = fmaxf(C[2] + bc, 0.f) * wf;
    float v3 = fmaxf(C[3] + bc, 0.f) * wf;
    #pragma unroll
    for (int o = 1; o < 16; o <<= 1) {
        v0 += __shfl_xor(v0, o, 64);
        v1 += __shfl_xor(v1, o, 64);
        v2 += __shfl_xor(v2, o, 64);
        v3 += __shfl_xor(v3, o, 64);
    }
    if (m == 0) {
        sRed[wid][quad * 4 + 0] = v0;
        sRed[wid][quad * 4 + 1] = v1;
        sRed[wid][quad * 4 + 2] = v2;
        sRed[wid][quad * 4 + 3] = v3;
    }
    __syncthreads();
    if (t < 16) {
        int ng = blockIdx.x * 16 + t;
        if (ng < N) {
            float tt = sRed[0][t] + sRed[1][t] + sRed[2][t] + sRed[3][t];
            float dj = sDi[t];
            // contribution: u_j * dinv_j * (dinv_j + q_j)
            double c = (double)(dj * tt * (dj + q[ng]));
            atomicAdd(&pool[ng & 255], c);
        }
    }
}

__global__ void k_final(const double* __restrict__ pool, const float* __restrict__ wfc,
                        const float* __restrict__ fcb, float* __restrict__ out, double invN) {
    __shared__ double s[256];
    int t = threadIdx.x;
    s[t] = pool[t];
    __syncthreads();
    for (int o = 128; o > 0; o >>= 1) {
        if (t < o) s[t] += s[t + o];
        __syncthreads();
    }
    if (t == 0) out[0] = (float)(s[0] * invN) + wfc[64] + fcb[0];
}

extern "C" void kernel_launch(void* const* d_in, const int* in_sizes, int n_in,
                              void* d_out, int out_size, void* d_ws, size_t ws_size,
                              hipStream_t stream) {
    const float* x   = (const float*)d_in[0];
    const int*   ei  = (const int*)d_in[1];
    const float* W1  = (const float*)d_in[2];
    const float* b1  = (const float*)d_in[3];
    const float* W2  = (const float*)d_in[4];
    const float* b2  = (const float*)d_in[5];
    const float* W3  = (const float*)d_in[6];
    const float* b3  = (const float*)d_in[7];
    const float* fcW = (const float*)d_in[8];
    const float* fcb = (const float*)d_in[9];

    const int N = in_sizes[0] / 10;
    const int E = in_sizes[1] / 2;
    const int* src = ei;
    const int* dst = ei + E;

    const int K   = (N + 255) >> 8;            // buckets of 256 nodes (196)
    const int NB  = (E + CHUNK - 1) / CHUNK;   // chunks (391)
    const int NBS = NB | 1;                    // odd stride

    // ---- workspace carve-up (256B aligned) ----
    char* w = (char*)d_ws;
    size_t off = 0;
    auto alloc = [&](size_t bytes) -> void* {
        void* p = w + off;
        off += (bytes + 255) & ~(size_t)255;
        return p;
    };
    int*      histT      = (int*)alloc((size_t)K * NBS * 4);
    int*      tot        = (int*)alloc((size_t)K * 4);
    int*      bucketBase = (int*)alloc((size_t)K * 4);
    int*      bucketCnt  = (int*)alloc((size_t)K * 4);
    unsigned* pairs      = (unsigned*)alloc((size_t)E * 4);
    unsigned short* col  = (unsigned short*)alloc((size_t)E * 2);
    int*      rowptr     = (int*)alloc((size_t)(N + 1) * 4);
    float*    dinv       = (float*)alloc((size_t)N * 4);
    float*    q          = (float*)alloc((size_t)N * 4);
    double*   pool       = (double*)alloc(256 * 8);
    float*    wfc        = (float*)alloc(65 * 4);
    __half*   gx         = (__half*)alloc((size_t)N * 16 * 2);
    __half*   g1         = (__half*)alloc((size_t)N * 64 * 2);   // interleaved h1, 128B/node
    (void)ws_size; (void)n_in; (void)out_size;

    const int nbNode16 = (N + 15) / 16;

    // ---- atomic-free CSR build (counting sort, LDS atomics only) ----
    k_hist   <<<NB, 1024, 0, stream>>>(dst, E, histT, K, NBS,
                                       W3, fcW, b3, wfc, pool, rowptr, q, N);
    k_tot    <<<K, 64, 0, stream>>>(histT, NB, NBS, tot);
    k_offsets<<<K, 256, 0, stream>>>(histT, NB, NBS, K, tot, bucketBase, bucketCnt);
    k_scatter<<<NB, 1024, 0, stream>>>(src, dst, E, histT, K, NBS, pairs);
    k_bucket <<<K, 1024, 0, stream>>>(pairs, bucketBase, bucketCnt, x,
                                      rowptr, dinv, gx, col, q, N);

    // ---- fused layers (layer 3 folded into k_L2 via q) ----
    k_L1 <<<nbNode16, 256, 0, stream>>>(gx, W1, b1, rowptr, col, dinv, g1, N);
    k_L2 <<<nbNode16, 256, 0, stream>>>(g1, W2, b2, wfc, rowptr, col, dinv, q, pool, N);
    k_final<<<1, 256, 0, stream>>>(pool, wfc, fcb, (float*)d_out, 1.0 / (double)N);
}

// Round 6
// 156.451 us; speedup vs baseline: 1.5621x; 1.1875x over previous
//
#include <hip/hip_runtime.h>
#include <hip/hip_fp16.h>

typedef _Float16 half8 __attribute__((ext_vector_type(8)));
typedef float float4v __attribute__((ext_vector_type(4)));

#define CHUNK 2048           // edges per hist/scatter block
#define BS    128            // nodes per bucket
#define BCAP  3072           // LDS staging capacity in k_bucket

// ========== phase 1: per-chunk LDS histogram (1024 thr) + misc init in block 0 ==========
__global__ void __launch_bounds__(1024) k_hist(
        const int* __restrict__ dst, int E, int* __restrict__ histT, int K, int NBS,
        const float* __restrict__ W3, const float* __restrict__ fcW,
        const float* __restrict__ b3, float* __restrict__ wfc,
        double* __restrict__ pool, int* __restrict__ rowptr, int N) {
    __shared__ int lh[512];
    int t = threadIdx.x, b = blockIdx.x;
    if (t < 512) lh[t] = 0;
    __syncthreads();
    int base = b * CHUNK;
    #pragma unroll
    for (int i = 0; i < 2; ++i) {
        int e = base + i * 1024 + t;
        if (e < E) atomicAdd(&lh[dst[e] >> 7], 1);   // LDS atomic
    }
    __syncthreads();
    if (t < K) histT[t * NBS + b] = lh[t];
    if (b == 0) {                                    // fold tiny init work here
        if (t < 256) pool[t] = 0.0;
        if (t == 0) rowptr[N] = E;
        if (t < 64) {                                // wfc[c]=(W3@fcW)[c]; wfc[64]=b3.fcW
            float v = 0.f;
            #pragma unroll 8
            for (int j = 0; j < 64; ++j) v += W3[t * 64 + j] * fcW[j];
            wfc[t] = v;
            float bb = b3[t] * fcW[t];
            for (int o = 32; o > 0; o >>= 1) bb += __shfl_down(bb, o, 64);
            if (t == 0) wfc[64] = bb;
        }
    }
}

// ========== phase 2a: per-bucket totals (one wave per bucket) ==========
__global__ void k_tot(const int* __restrict__ histT, int NB, int NBS, int* __restrict__ tot) {
    int k = blockIdx.x, t = threadIdx.x;
    int s = 0;
    for (int b = t; b < NB; b += 64) s += histT[k * NBS + b];
    for (int o = 32; o > 0; o >>= 1) s += __shfl_down(s, o, 64);
    if (t == 0) tot[k] = s;
}

// ========== phase 2b: bucket base via block reduction + chunk-offset row scan ==========
__global__ void k_offsets(int* __restrict__ histT, int NB, int NBS, int K,
                          const int* __restrict__ tot,
                          int* __restrict__ bucketBase, int* __restrict__ bucketCnt) {
    __shared__ int sc[256], red[256];
    int k = blockIdx.x, t = threadIdx.x;
    // exclusive prefix at bucket k: sum of tot[0..k-1]
    int c = 0;
    for (int j = t; j < k; j += 256) c += tot[j];
    red[t] = c;
    __syncthreads();
    for (int o = 128; o > 0; o >>= 1) {
        if (t < o) red[t] += red[t + o];
        __syncthreads();
    }
    int carry = red[0];
    if (t == 0) { bucketBase[k] = carry; bucketCnt[k] = tot[k]; }
    // scan own row (chunk offsets within bucket)
    for (int tile = 0; tile < NB; tile += 256) {
        int b = tile + t;
        int hv = (b < NB) ? histT[k * NBS + b] : 0;
        __syncthreads();
        sc[t] = hv;
        __syncthreads();
        for (int o = 1; o < 256; o <<= 1) {
            int u = (t >= o) ? sc[t - o] : 0;
            __syncthreads();
            sc[t] += u;
            __syncthreads();
        }
        if (b < NB) histT[k * NBS + b] = carry + sc[t] - hv;
        carry += sc[255];
    }
}

// ========== phase 3: scatter edges into bucket-partitioned pairs (1024 thr) ==========
__global__ void __launch_bounds__(1024) k_scatter(
        const int* __restrict__ src, const int* __restrict__ dst, int E,
        const int* __restrict__ histT, int K, int NBS, unsigned* __restrict__ pairs) {
    __shared__ int cur[512];
    int t = threadIdx.x, b = blockIdx.x;
    if (t < K) cur[t] = histT[t * NBS + b];
    __syncthreads();
    int base = b * CHUNK;
    #pragma unroll
    for (int i = 0; i < 2; ++i) {
        int e = base + i * 1024 + t;
        if (e < E) {
            int d = dst[e];
            int pos = atomicAdd(&cur[d >> 7], 1);    // LDS atomic
            pairs[pos] = ((unsigned)(d & 127) << 16) | (unsigned)src[e];
        }
    }
}

// ========== phase 4: per-bucket exact CSR + rowptr/dinv/gx (1024 thr, 128-node bucket) ==========
__global__ void __launch_bounds__(1024) k_bucket(
        const unsigned* __restrict__ pairs, const int* __restrict__ bucketBase,
        const int* __restrict__ bucketCnt, const float* __restrict__ x,
        int* __restrict__ rowptr, float* __restrict__ dinv,
        __half* __restrict__ gx, unsigned short* __restrict__ col, int N) {
    __shared__ unsigned pl[BCAP];
    __shared__ int h[BS], nb[BS], cur[BS];
    __shared__ float sdi[BS];
    int k = blockIdx.x, t = threadIdx.x;
    int base = bucketBase[k], cnt = bucketCnt[k];
    bool stg = cnt <= BCAP;
    if (t < BS) h[t] = 0;
    if (stg) for (int i = t; i < cnt; i += 1024) pl[i] = pairs[base + i];
    __syncthreads();
    for (int i = t; i < cnt; i += 1024) {
        unsigned p = stg ? pl[i] : pairs[base + i];
        atomicAdd(&h[p >> 16], 1);                   // LDS atomic
    }
    __syncthreads();
    int d = (t < BS) ? h[t] : 0;
    if (t < BS) nb[t] = d;
    __syncthreads();
    for (int o = 1; o < BS; o <<= 1) {
        int v = (t < BS && t >= o) ? nb[t - o] : 0;
        __syncthreads();
        if (t < BS) nb[t] += v;
        __syncthreads();
    }
    if (t < BS) {
        int excl = nb[t] - d;
        cur[t] = excl;
        int gid = (k << 7) + t;
        if (gid < N) {
            rowptr[gid] = base + excl;
            float di = rsqrtf((float)(d + 1));       // +1 self loop
            dinv[gid] = di;
            sdi[t] = di;
        }
    }
    __syncthreads();
    // gx fill: BS nodes x 16 halfs, spread across all 1024 threads
    for (int i = t; i < BS * 16; i += 1024) {
        int nl = i >> 4, q2 = i & 15;
        int gid = (k << 7) + nl;
        if (gid < N)
            gx[(unsigned)gid * 16 + q2] =
                __float2half(q2 < 10 ? x[gid * 10 + q2] * sdi[nl] : 0.f);
    }
    // placement
    for (int i = t; i < cnt; i += 1024) {
        unsigned p = stg ? pl[i] : pairs[base + i];
        int j = p >> 16;
        int pos = atomicAdd(&cur[j], 1);             // LDS atomic
        col[base + pos] = (unsigned short)(p & 0xFFFFu);
    }
}

// ========== layer 1: gather gx16 (1.6MB, L2-resident), 16 lanes/node ==========
// output: interleaved g1 (128B/node): lane f's 4 output feats at byte offset f*8
__global__ void k_L1(const __half* __restrict__ gx, const float* __restrict__ W1,
                     const float* __restrict__ b1, const int* __restrict__ rowptr,
                     const unsigned short* __restrict__ col, const float* __restrict__ dinv,
                     __half* __restrict__ g1, int N) {
    __shared__ float sW[10 * 64];
    __shared__ float sB[64];
    int t = threadIdx.x;
    for (int i = t; i < 640; i += 256) sW[i] = W1[i];
    if (t < 64) sB[t] = b1[t];
    __syncthreads();
    int node = blockIdx.x * 16 + (t >> 4);
    int f = t & 15;
    bool live = node < N;
    bool act = live && (f < 10);
    const char* gp = (const char*)gx;
    unsigned fo = (unsigned)(f << 1);
    float di = live ? dinv[node] : 0.f;
    float a = act ? __half2float(*(const __half*)(gp + ((unsigned)node << 5) + fo)) : 0.f;
    int s0 = 0, s1 = 0;
    if (live) { s0 = rowptr[node]; s1 = rowptr[node + 1]; }
    int e = s0;
    for (; e + 4 <= s1; e += 4) {
        unsigned j0 = col[e], j1 = col[e + 1], j2 = col[e + 2], j3 = col[e + 3];
        float v0 = 0.f, v1 = 0.f, v2 = 0.f, v3 = 0.f;
        if (act) {
            v0 = __half2float(*(const __half*)(gp + (j0 << 5) + fo));
            v1 = __half2float(*(const __half*)(gp + (j1 << 5) + fo));
            v2 = __half2float(*(const __half*)(gp + (j2 << 5) + fo));
            v3 = __half2float(*(const __half*)(gp + (j3 << 5) + fo));
        }
        a += (v0 + v1) + (v2 + v3);
    }
    for (; e < s1; ++e) {
        unsigned j = col[e];
        if (act) a += __half2float(*(const __half*)(gp + (j << 5) + fo));
    }
    a *= di;                                   // P_i(x)[f], f<10
    int gb = t & 48;
    float c0 = 0.f, c1 = 0.f, c2 = 0.f, c3 = 0.f;
    int c4 = 4 * f;
    #pragma unroll
    for (int k = 0; k < 10; ++k) {
        float ak = __shfl(a, gb + k, 64);
        c0 += ak * sW[k * 64 + c4];
        c1 += ak * sW[k * 64 + c4 + 1];
        c2 += ak * sW[k * 64 + c4 + 2];
        c3 += ak * sW[k * 64 + c4 + 3];
    }
    if (!live) return;
    float h0 = di * fmaxf(c0 + sB[c4], 0.f);
    float h1 = di * fmaxf(c1 + sB[c4 + 1], 0.f);
    float h2 = di * fmaxf(c2 + sB[c4 + 2], 0.f);
    float h3 = di * fmaxf(c3 + sB[c4 + 3], 0.f);
    union { __half h[4]; uint2 u; } pk;
    pk.h[0] = __float2half(h0); pk.h[1] = __float2half(h1);
    pk.h[2] = __float2half(h2); pk.h[3] = __float2half(h3);
    *(uint2*)((char*)g1 + ((unsigned)node << 7) + (unsigned)(f << 3)) = pk.u;
}

// ========== layer 2 (merged): single gather over g1 (6.4MB) + MFMA epilogue -> tvec ==========
__global__ void __launch_bounds__(256) k_L2(
        const __half* __restrict__ g1,
        const float* __restrict__ W2, const float* __restrict__ b2,
        const float* __restrict__ wfcv, const int* __restrict__ rowptr,
        const unsigned short* __restrict__ col, const float* __restrict__ dinv,
        float* __restrict__ tvec, int N) {
    __shared__ __align__(16) __half At[16 * 72];   // 16 nodes x 64 feats, stride 72
    __shared__ float sRed[4][16];
    __shared__ float sDi[16];
    int t = threadIdx.x;
    int lane = t & 63, wid = t >> 6;
    int m = lane & 15, quad = lane >> 4;

    // B fragments: W2 column cg, fp16 hi/lo split (registers, overlaps gather)
    int cg = (wid << 4) + m;
    half8 H0, L0, H1, L1;
    #pragma unroll
    for (int j = 0; j < 8; ++j) {
        float w0 = W2[(quad * 8 + j) * 64 + cg];
        _Float16 h0 = (_Float16)w0;
        H0[j] = h0; L0[j] = (_Float16)(w0 - (float)h0);
        float w1 = W2[(32 + quad * 8 + j) * 64 + cg];
        _Float16 h1 = (_Float16)w1;
        H1[j] = h1; L1[j] = (_Float16)(w1 - (float)h1);
    }
    float bc = b2[cg], wf = wfcv[cg];

    // gather g1: 16 nodes/block, 16 lanes/node, 4 feats (uint2, 8B) per lane
    int nl = t >> 4, f4 = t & 15;
    int node = blockIdx.x * 16 + nl;
    bool live = node < N;
    float di = live ? dinv[node] : 0.f;
    float ax = 0.f, ay = 0.f, az = 0.f, aw = 0.f;
    if (live) {
        const char* gp = (const char*)g1;
        unsigned fo = (unsigned)(f4 << 3);
        uint2 us = *(const uint2*)(gp + ((unsigned)node << 7) + fo);
        float2 slo = __half22float2(*(__half2*)&us.x);
        float2 shi = __half22float2(*(__half2*)&us.y);
        ax = slo.x; ay = slo.y; az = shi.x; aw = shi.y;
        int s0 = rowptr[node], s1 = rowptr[node + 1];
        int e = s0;
        for (; e + 8 <= s1; e += 8) {
            unsigned j0 = col[e],     j1 = col[e + 1], j2 = col[e + 2], j3 = col[e + 3];
            unsigned j4 = col[e + 4], j5 = col[e + 5], j6 = col[e + 6], j7 = col[e + 7];
            uint2 u0 = *(const uint2*)(gp + (j0 << 7) + fo);
            uint2 u1 = *(const uint2*)(gp + (j1 << 7) + fo);
            uint2 u2 = *(const uint2*)(gp + (j2 << 7) + fo);
            uint2 u3 = *(const uint2*)(gp + (j3 << 7) + fo);
            uint2 u4 = *(const uint2*)(gp + (j4 << 7) + fo);
            uint2 u5 = *(const uint2*)(gp + (j5 << 7) + fo);
            uint2 u6 = *(const uint2*)(gp + (j6 << 7) + fo);
            uint2 u7 = *(const uint2*)(gp + (j7 << 7) + fo);
            float2 a0 = __half22float2(*(__half2*)&u0.x), b0 = __half22float2(*(__half2*)&u0.y);
            float2 a1 = __half22float2(*(__half2*)&u1.x), b1v = __half22float2(*(__half2*)&u1.y);
            float2 a2 = __half22float2(*(__half2*)&u2.x), b2v = __half22float2(*(__half2*)&u2.y);
            float2 a3 = __half22float2(*(__half2*)&u3.x), b3v = __half22float2(*(__half2*)&u3.y);
            float2 a4 = __half22float2(*(__half2*)&u4.x), b4 = __half22float2(*(__half2*)&u4.y);
            float2 a5 = __half22float2(*(__half2*)&u5.x), b5 = __half22float2(*(__half2*)&u5.y);
            float2 a6 = __half22float2(*(__half2*)&u6.x), b6 = __half22float2(*(__half2*)&u6.y);
            float2 a7 = __half22float2(*(__half2*)&u7.x), b7 = __half22float2(*(__half2*)&u7.y);
            ax += ((a0.x + a1.x) + (a2.x + a3.x)) + ((a4.x + a5.x) + (a6.x + a7.x));
            ay += ((a0.y + a1.y) + (a2.y + a3.y)) + ((a4.y + a5.y) + (a6.y + a7.y));
            az += ((b0.x + b1v.x) + (b2v.x + b3v.x)) + ((b4.x + b5.x) + (b6.x + b7.x));
            aw += ((b0.y + b1v.y) + (b2v.y + b3v.y)) + ((b4.y + b5.y) + (b6.y + b7.y));
        }
        for (; e < s1; ++e) {
            uint2 u0 = *(const uint2*)(gp + ((unsigned)col[e] << 7) + fo);
            float2 a0 = __half22float2(*(__half2*)&u0.x), b0 = __half22float2(*(__half2*)&u0.y);
            ax += a0.x; ay += a0.y; az += b0.x; aw += b0.y;
        }
    }
    union { __half h[4]; uint2 u; } pk;
    pk.h[0] = __float2half(ax * di); pk.h[1] = __float2half(ay * di);
    pk.h[2] = __float2half(az * di); pk.h[3] = __float2half(aw * di);
    *(uint2*)&At[nl * 72 + 4 * f4] = pk.u;    // feats 4*f4 .. 4*f4+3 of node nl
    if (f4 == 0) sDi[nl] = di;
    __syncthreads();

    // MFMA: D[m=node][n=col] = A(16x64) @ W2(64x64); this wave: cols 16*wid..
    half8 A0 = *reinterpret_cast<const half8*>(&At[m * 72 + quad * 8]);
    half8 A1 = *reinterpret_cast<const half8*>(&At[m * 72 + 32 + quad * 8]);
    float4v C = {0.f, 0.f, 0.f, 0.f};
    C = __builtin_amdgcn_mfma_f32_16x16x32_f16(A0, H0, C, 0, 0, 0);
    C = __builtin_amdgcn_mfma_f32_16x16x32_f16(A0, L0, C, 0, 0, 0);
    C = __builtin_amdgcn_mfma_f32_16x16x32_f16(A1, H1, C, 0, 0, 0);
    C = __builtin_amdgcn_mfma_f32_16x16x32_f16(A1, L1, C, 0, 0, 0);

    // epilogue: relu(C+b2)*wfc, reduce over cols -> per-node scalar
    float v0 = fmaxf(C[0] + bc, 0.f) * wf;
    float v1 = fmaxf(C[1] + bc, 0.f) * wf;
    float v2 = fmaxf(C[2] + bc, 0.f) * wf;
    float v3 = fmaxf(C[3] + bc, 0.f) * wf;
    #pragma unroll
    for (int o = 1; o < 16; o <<= 1) {
        v0 += __shfl_xor(v0, o, 64);
        v1 += __shfl_xor(v1, o, 64);
        v2 += __shfl_xor(v2, o, 64);
        v3 += __shfl_xor(v3, o, 64);
    }
    if (m == 0) {
        sRed[wid][quad * 4 + 0] = v0;
        sRed[wid][quad * 4 + 1] = v1;
        sRed[wid][quad * 4 + 2] = v2;
        sRed[wid][quad * 4 + 3] = v3;
    }
    __syncthreads();
    if (t < 16) {
        int ng = blockIdx.x * 16 + t;
        if (ng < N) {
            float tt = sRed[0][t] + sRed[1][t] + sRed[2][t] + sRed[3][t];
            tvec[ng] = sDi[t] * tt;            // t_j = dinv_j * (h2_j . wfc)
        }
    }
}

// ========== layer 3: scalar gather over tvec (200KB) + mean-pool ==========
__global__ void k_agg3(const float* __restrict__ tvec, const int* __restrict__ rowptr,
                       const unsigned short* __restrict__ col, const float* __restrict__ dinv,
                       double* __restrict__ pool, int N) {
    int tid = blockIdx.x * 256 + threadIdx.x;
    int node = tid >> 4, lane = tid & 15;
    if (node >= N) return;
    int s0 = rowptr[node], s1 = rowptr[node + 1];
    float s = 0.f;
    for (int e = s0 + lane; e < s1; e += 16) s += tvec[col[e]];
    #pragma unroll
    for (int o = 1; o < 16; o <<= 1) s += __shfl_xor(s, o, 64);
    if (lane == 0) {
        double contrib = (double)(dinv[node] * (tvec[node] + s));
        atomicAdd(&pool[node & 255], contrib);
    }
}

__global__ void k_final(const double* __restrict__ pool, const float* __restrict__ wfc,
                        const float* __restrict__ fcb, float* __restrict__ out, double invN) {
    __shared__ double s[256];
    int t = threadIdx.x;
    s[t] = pool[t];
    __syncthreads();
    for (int o = 128; o > 0; o >>= 1) {
        if (t < o) s[t] += s[t + o];
        __syncthreads();
    }
    if (t == 0) out[0] = (float)(s[0] * invN) + wfc[64] + fcb[0];
}

extern "C" void kernel_launch(void* const* d_in, const int* in_sizes, int n_in,
                              void* d_out, int out_size, void* d_ws, size_t ws_size,
                              hipStream_t stream) {
    const float* x   = (const float*)d_in[0];
    const int*   ei  = (const int*)d_in[1];
    const float* W1  = (const float*)d_in[2];
    const float* b1  = (const float*)d_in[3];
    const float* W2  = (const float*)d_in[4];
    const float* b2  = (const float*)d_in[5];
    const float* W3  = (const float*)d_in[6];
    const float* b3  = (const float*)d_in[7];
    const float* fcW = (const float*)d_in[8];
    const float* fcb = (const float*)d_in[9];

    const int N = in_sizes[0] / 10;
    const int E = in_sizes[1] / 2;
    const int* src = ei;
    const int* dst = ei + E;

    const int K   = (N + BS - 1) >> 7;         // buckets of 128 nodes (391)
    const int NB  = (E + CHUNK - 1) / CHUNK;   // chunks (391)
    const int NBS = NB | 1;                    // odd stride

    // ---- workspace carve-up (256B aligned) ----
    char* w = (char*)d_ws;
    size_t off = 0;
    auto alloc = [&](size_t bytes) -> void* {
        void* p = w + off;
        off += (bytes + 255) & ~(size_t)255;
        return p;
    };
    int*      histT      = (int*)alloc((size_t)K * NBS * 4);
    int*      tot        = (int*)alloc((size_t)K * 4);
    int*      bucketBase = (int*)alloc((size_t)K * 4);
    int*      bucketCnt  = (int*)alloc((size_t)K * 4);
    unsigned* pairs      = (unsigned*)alloc((size_t)E * 4);
    unsigned short* col  = (unsigned short*)alloc((size_t)E * 2);
    int*      rowptr     = (int*)alloc((size_t)(N + 1) * 4);
    float*    dinv       = (float*)alloc((size_t)N * 4);
    double*   pool       = (double*)alloc(256 * 8);
    float*    wfc        = (float*)alloc(65 * 4);
    float*    tvec       = (float*)alloc((size_t)N * 4);
    __half*   gx         = (__half*)alloc((size_t)N * 16 * 2);
    __half*   g1         = (__half*)alloc((size_t)N * 64 * 2);   // interleaved h1, 128B/node
    (void)ws_size; (void)n_in; (void)out_size;

    const int nbNode16 = (N + 15) / 16;

    // ---- atomic-free CSR build (counting sort, LDS atomics only) ----
    k_hist   <<<NB, 1024, 0, stream>>>(dst, E, histT, K, NBS,
                                       W3, fcW, b3, wfc, pool, rowptr, N);
    k_tot    <<<K, 64, 0, stream>>>(histT, NB, NBS, tot);
    k_offsets<<<K, 256, 0, stream>>>(histT, NB, NBS, K, tot, bucketBase, bucketCnt);
    k_scatter<<<NB, 1024, 0, stream>>>(src, dst, E, histT, K, NBS, pairs);
    k_bucket <<<K, 1024, 0, stream>>>(pairs, bucketBase, bucketCnt, x,
                                      rowptr, dinv, gx, col, N);

    // ---- fused layers ----
    k_L1 <<<nbNode16, 256, 0, stream>>>(gx, W1, b1, rowptr, col, dinv, g1, N);
    k_L2 <<<nbNode16, 256, 0, stream>>>(g1, W2, b2, wfc, rowptr, col, dinv, tvec, N);
    k_agg3<<<nbNode16, 256, 0, stream>>>(tvec, rowptr, col, dinv, pool, N);
    k_final<<<1, 256, 0, stream>>>(pool, wfc, fcb, (float*)d_out, 1.0 / (double)N);
}

// Round 7
// 156.024 us; speedup vs baseline: 1.5664x; 1.0027x over previous
//
#include <hip/hip_runtime.h>
#include <hip/hip_fp16.h>

typedef _Float16 half8 __attribute__((ext_vector_type(8)));
typedef float float4v __attribute__((ext_vector_type(4)));

#define CHUNK 2048           // edges per hist/scatter block
#define BS    128            // nodes per bucket
#define BCAP  3072           // LDS staging capacity in k_bucket

// ========== phase 1: per-chunk LDS histogram + bucket-prefix (1024 thr) ==========
__global__ void __launch_bounds__(1024) k_hist(
        const int* __restrict__ dst, int E, int* __restrict__ histT,
        int* __restrict__ histP, int K, int NBS,
        const float* __restrict__ W3, const float* __restrict__ fcW,
        const float* __restrict__ b3, float* __restrict__ wfc,
        double* __restrict__ pool, int* __restrict__ rowptr, int N) {
    __shared__ int lh[512];
    __shared__ int sp[512];
    int t = threadIdx.x, b = blockIdx.x;
    if (t < 512) lh[t] = 0;
    __syncthreads();
    int base = b * CHUNK;
    #pragma unroll
    for (int i = 0; i < 2; ++i) {
        int e = base + i * 1024 + t;
        if (e < E) atomicAdd(&lh[dst[e] >> 7], 1);   // LDS atomic
    }
    __syncthreads();
    // inclusive scan over lh[0..511] (Hillis-Steele, 512 wide)
    if (t < 512) sp[t] = lh[t];
    __syncthreads();
    for (int o = 1; o < 512; o <<= 1) {
        int u = (t < 512 && t >= o) ? sp[t - o] : 0;
        __syncthreads();
        if (t < 512) sp[t] += u;
        __syncthreads();
    }
    if (t < K) {
        histT[t * NBS + b] = lh[t];
        histP[t * NBS + b] = sp[t] - lh[t];          // exclusive prefix over buckets
    }
    if (b == 0) {                                    // fold tiny init work here
        if (t < 256) pool[t] = 0.0;
        if (t == 0) rowptr[N] = E;
        if (t < 64) {                                // wfc[c]=(W3@fcW)[c]; wfc[64]=b3.fcW
            float v = 0.f;
            #pragma unroll 8
            for (int j = 0; j < 64; ++j) v += W3[t * 64 + j] * fcW[j];
            wfc[t] = v;
            float bb = b3[t] * fcW[t];
            for (int o = 32; o > 0; o >>= 1) bb += __shfl_down(bb, o, 64);
            if (t == 0) wfc[64] = bb;
        }
    }
}

// ========== phase 2: bucket base/cnt via row reduces + chunk-offset row scan ==========
__global__ void k_offsets(int* __restrict__ histT, const int* __restrict__ histP,
                          int NB, int NBS, int K,
                          int* __restrict__ bucketBase, int* __restrict__ bucketCnt) {
    __shared__ int sc[256];
    int k = blockIdx.x, t = threadIdx.x;
    // row reduces: base = sum histP[k][:]  (= sum of totals of buckets < k)
    //              cnt  = sum histT[k][:]
    int sb = 0, st = 0;
    for (int b = t; b < NB; b += 256) {
        sb += histP[k * NBS + b];
        st += histT[k * NBS + b];
    }
    sc[t] = sb;
    __syncthreads();
    for (int o = 128; o > 0; o >>= 1) {
        if (t < o) sc[t] += sc[t + o];
        __syncthreads();
    }
    int bbase = sc[0];
    __syncthreads();
    sc[t] = st;
    __syncthreads();
    for (int o = 128; o > 0; o >>= 1) {
        if (t < o) sc[t] += sc[t + o];
        __syncthreads();
    }
    int cnt = sc[0];
    __syncthreads();
    if (t == 0) { bucketBase[k] = bbase; bucketCnt[k] = cnt; }
    // scan own row (chunk offsets within bucket)
    int carry = bbase;
    for (int tile = 0; tile < NB; tile += 256) {
        int b = tile + t;
        int hv = (b < NB) ? histT[k * NBS + b] : 0;
        __syncthreads();
        sc[t] = hv;
        __syncthreads();
        for (int o = 1; o < 256; o <<= 1) {
            int u = (t >= o) ? sc[t - o] : 0;
            __syncthreads();
            sc[t] += u;
            __syncthreads();
        }
        if (b < NB) histT[k * NBS + b] = carry + sc[t] - hv;
        carry += sc[255];
    }
}

// ========== phase 3: scatter edges into bucket-partitioned pairs (1024 thr) ==========
__global__ void __launch_bounds__(1024) k_scatter(
        const int* __restrict__ src, const int* __restrict__ dst, int E,
        const int* __restrict__ histT, int K, int NBS, unsigned* __restrict__ pairs) {
    __shared__ int cur[512];
    int t = threadIdx.x, b = blockIdx.x;
    if (t < K) cur[t] = histT[t * NBS + b];
    __syncthreads();
    int base = b * CHUNK;
    #pragma unroll
    for (int i = 0; i < 2; ++i) {
        int e = base + i * 1024 + t;
        if (e < E) {
            int d = dst[e];
            int pos = atomicAdd(&cur[d >> 7], 1);    // LDS atomic
            pairs[pos] = ((unsigned)(d & 127) << 16) | (unsigned)src[e];
        }
    }
}

// ========== phase 4: per-bucket exact CSR + rowptr/dinv/gx (1024 thr, 128-node bucket) ==========
__global__ void __launch_bounds__(1024) k_bucket(
        const unsigned* __restrict__ pairs, const int* __restrict__ bucketBase,
        const int* __restrict__ bucketCnt, const float* __restrict__ x,
        int* __restrict__ rowptr, float* __restrict__ dinv,
        __half* __restrict__ gx, unsigned short* __restrict__ col, int N) {
    __shared__ unsigned pl[BCAP];
    __shared__ unsigned short scol[BCAP];
    __shared__ int h[BS], nb[BS], cur[BS];
    __shared__ float sdi[BS];
    int k = blockIdx.x, t = threadIdx.x;
    int base = bucketBase[k], cnt = bucketCnt[k];
    bool stg = cnt <= BCAP;
    if (t < BS) h[t] = 0;
    if (stg) for (int i = t; i < cnt; i += 1024) pl[i] = pairs[base + i];
    __syncthreads();
    for (int i = t; i < cnt; i += 1024) {
        unsigned p = stg ? pl[i] : pairs[base + i];
        atomicAdd(&h[p >> 16], 1);                   // LDS atomic
    }
    __syncthreads();
    int d = (t < BS) ? h[t] : 0;
    if (t < BS) nb[t] = d;
    __syncthreads();
    for (int o = 1; o < BS; o <<= 1) {
        int v = (t < BS && t >= o) ? nb[t - o] : 0;
        __syncthreads();
        if (t < BS) nb[t] += v;
        __syncthreads();
    }
    if (t < BS) {
        int excl = nb[t] - d;
        cur[t] = excl;
        int gid = (k << 7) + t;
        if (gid < N) {
            rowptr[gid] = base + excl;
            float di = rsqrtf((float)(d + 1));       // +1 self loop
            dinv[gid] = di;
            sdi[t] = di;
        }
    }
    __syncthreads();
    // gx fill: BS nodes x 16 halfs, spread across all 1024 threads
    for (int i = t; i < BS * 16; i += 1024) {
        int nl = i >> 4, q2 = i & 15;
        int gid = (k << 7) + nl;
        if (gid < N)
            gx[(unsigned)gid * 16 + q2] =
                __float2half(q2 < 10 ? x[gid * 10 + q2] * sdi[nl] : 0.f);
    }
    // placement: scatter into LDS, then stream out coalesced
    for (int i = t; i < cnt; i += 1024) {
        unsigned p = stg ? pl[i] : pairs[base + i];
        int j = p >> 16;
        int pos = atomicAdd(&cur[j], 1);             // LDS atomic
        if (stg) scol[pos] = (unsigned short)(p & 0xFFFFu);
        else     col[base + pos] = (unsigned short)(p & 0xFFFFu);
    }
    __syncthreads();
    if (stg) for (int i = t; i < cnt; i += 1024) col[base + i] = scol[i];
}

// ========== layer 1: gather gx16 (1.6MB, L2-resident), 16 lanes/node ==========
// output: interleaved g1 (128B/node): lane f's 4 output feats at byte offset f*8
__global__ void k_L1(const __half* __restrict__ gx, const float* __restrict__ W1,
                     const float* __restrict__ b1, const int* __restrict__ rowptr,
                     const unsigned short* __restrict__ col, const float* __restrict__ dinv,
                     __half* __restrict__ g1, int N) {
    __shared__ float sW[10 * 64];
    __shared__ float sB[64];
    int t = threadIdx.x;
    for (int i = t; i < 640; i += 256) sW[i] = W1[i];
    if (t < 64) sB[t] = b1[t];
    __syncthreads();
    int node = blockIdx.x * 16 + (t >> 4);
    int f = t & 15;
    bool live = node < N;
    bool act = live && (f < 10);
    const char* gp = (const char*)gx;
    unsigned fo = (unsigned)(f << 1);
    float di = live ? dinv[node] : 0.f;
    float a = act ? __half2float(*(const __half*)(gp + ((unsigned)node << 5) + fo)) : 0.f;
    int s0 = 0, s1 = 0;
    if (live) { s0 = rowptr[node]; s1 = rowptr[node + 1]; }
    int e = s0;
    for (; e + 4 <= s1; e += 4) {
        unsigned j0 = col[e], j1 = col[e + 1], j2 = col[e + 2], j3 = col[e + 3];
        float v0 = 0.f, v1 = 0.f, v2 = 0.f, v3 = 0.f;
        if (act) {
            v0 = __half2float(*(const __half*)(gp + (j0 << 5) + fo));
            v1 = __half2float(*(const __half*)(gp + (j1 << 5) + fo));
            v2 = __half2float(*(const __half*)(gp + (j2 << 5) + fo));
            v3 = __half2float(*(const __half*)(gp + (j3 << 5) + fo));
        }
        a += (v0 + v1) + (v2 + v3);
    }
    for (; e < s1; ++e) {
        unsigned j = col[e];
        if (act) a += __half2float(*(const __half*)(gp + (j << 5) + fo));
    }
    a *= di;                                   // P_i(x)[f], f<10
    int gb = t & 48;
    float c0 = 0.f, c1 = 0.f, c2 = 0.f, c3 = 0.f;
    int c4 = 4 * f;
    #pragma unroll
    for (int k = 0; k < 10; ++k) {
        float ak = __shfl(a, gb + k, 64);
        c0 += ak * sW[k * 64 + c4];
        c1 += ak * sW[k * 64 + c4 + 1];
        c2 += ak * sW[k * 64 + c4 + 2];
        c3 += ak * sW[k * 64 + c4 + 3];
    }
    if (!live) return;
    float h0 = di * fmaxf(c0 + sB[c4], 0.f);
    float h1 = di * fmaxf(c1 + sB[c4 + 1], 0.f);
    float h2 = di * fmaxf(c2 + sB[c4 + 2], 0.f);
    float h3 = di * fmaxf(c3 + sB[c4 + 3], 0.f);
    union { __half h[4]; uint2 u; } pk;
    pk.h[0] = __float2half(h0); pk.h[1] = __float2half(h1);
    pk.h[2] = __float2half(h2); pk.h[3] = __float2half(h3);
    *(uint2*)((char*)g1 + ((unsigned)node << 7) + (unsigned)(f << 3)) = pk.u;
}

// ========== layer 2 (merged): single gather over g1 (6.4MB) + MFMA epilogue -> tvec ==========
__global__ void __launch_bounds__(256) k_L2(
        const __half* __restrict__ g1,
        const float* __restrict__ W2, const float* __restrict__ b2,
        const float* __restrict__ wfcv, const int* __restrict__ rowptr,
        const unsigned short* __restrict__ col, const float* __restrict__ dinv,
        float* __restrict__ tvec, int N) {
    __shared__ __align__(16) __half At[16 * 72];   // 16 nodes x 64 feats, stride 72
    __shared__ float sRed[4][16];
    __shared__ float sDi[16];
    int t = threadIdx.x;
    int lane = t & 63, wid = t >> 6;
    int m = lane & 15, quad = lane >> 4;

    // B fragments: W2 column cg, fp16 hi/lo split (registers, overlaps gather)
    int cg = (wid << 4) + m;
    half8 H0, L0, H1, L1;
    #pragma unroll
    for (int j = 0; j < 8; ++j) {
        float w0 = W2[(quad * 8 + j) * 64 + cg];
        _Float16 h0 = (_Float16)w0;
        H0[j] = h0; L0[j] = (_Float16)(w0 - (float)h0);
        float w1 = W2[(32 + quad * 8 + j) * 64 + cg];
        _Float16 h1 = (_Float16)w1;
        H1[j] = h1; L1[j] = (_Float16)(w1 - (float)h1);
    }
    float bc = b2[cg], wf = wfcv[cg];

    // gather g1: 16 nodes/block, 16 lanes/node, 4 feats (uint2, 8B) per lane
    int nl = t >> 4, f4 = t & 15;
    int node = blockIdx.x * 16 + nl;
    bool live = node < N;
    float di = live ? dinv[node] : 0.f;
    float ax = 0.f, ay = 0.f, az = 0.f, aw = 0.f;
    if (live) {
        const char* gp = (const char*)g1;
        unsigned fo = (unsigned)(f4 << 3);
        uint2 us = *(const uint2*)(gp + ((unsigned)node << 7) + fo);
        float2 slo = __half22float2(*(__half2*)&us.x);
        float2 shi = __half22float2(*(__half2*)&us.y);
        ax = slo.x; ay = slo.y; az = shi.x; aw = shi.y;
        int s0 = rowptr[node], s1 = rowptr[node + 1];
        int e = s0;
        for (; e + 8 <= s1; e += 8) {
            unsigned j0 = col[e],     j1 = col[e + 1], j2 = col[e + 2], j3 = col[e + 3];
            unsigned j4 = col[e + 4], j5 = col[e + 5], j6 = col[e + 6], j7 = col[e + 7];
            uint2 u0 = *(const uint2*)(gp + (j0 << 7) + fo);
            uint2 u1 = *(const uint2*)(gp + (j1 << 7) + fo);
            uint2 u2 = *(const uint2*)(gp + (j2 << 7) + fo);
            uint2 u3 = *(const uint2*)(gp + (j3 << 7) + fo);
            uint2 u4 = *(const uint2*)(gp + (j4 << 7) + fo);
            uint2 u5 = *(const uint2*)(gp + (j5 << 7) + fo);
            uint2 u6 = *(const uint2*)(gp + (j6 << 7) + fo);
            uint2 u7 = *(const uint2*)(gp + (j7 << 7) + fo);
            float2 a0 = __half22float2(*(__half2*)&u0.x), b0 = __half22float2(*(__half2*)&u0.y);
            float2 a1 = __half22float2(*(__half2*)&u1.x), b1v = __half22float2(*(__half2*)&u1.y);
            float2 a2 = __half22float2(*(__half2*)&u2.x), b2v = __half22float2(*(__half2*)&u2.y);
            float2 a3 = __half22float2(*(__half2*)&u3.x), b3v = __half22float2(*(__half2*)&u3.y);
            float2 a4 = __half22float2(*(__half2*)&u4.x), b4 = __half22float2(*(__half2*)&u4.y);
            float2 a5 = __half22float2(*(__half2*)&u5.x), b5 = __half22float2(*(__half2*)&u5.y);
            float2 a6 = __half22float2(*(__half2*)&u6.x), b6 = __half22float2(*(__half2*)&u6.y);
            float2 a7 = __half22float2(*(__half2*)&u7.x), b7 = __half22float2(*(__half2*)&u7.y);
            ax += ((a0.x + a1.x) + (a2.x + a3.x)) + ((a4.x + a5.x) + (a6.x + a7.x));
            ay += ((a0.y + a1.y) + (a2.y + a3.y)) + ((a4.y + a5.y) + (a6.y + a7.y));
            az += ((b0.x + b1v.x) + (b2v.x + b3v.x)) + ((b4.x + b5.x) + (b6.x + b7.x));
            aw += ((b0.y + b1v.y) + (b2v.y + b3v.y)) + ((b4.y + b5.y) + (b6.y + b7.y));
        }
        for (; e < s1; ++e) {
            uint2 u0 = *(const uint2*)(gp + ((unsigned)col[e] << 7) + fo);
            float2 a0 = __half22float2(*(__half2*)&u0.x), b0 = __half22float2(*(__half2*)&u0.y);
            ax += a0.x; ay += a0.y; az += b0.x; aw += b0.y;
        }
    }
    union { __half h[4]; uint2 u; } pk;
    pk.h[0] = __float2half(ax * di); pk.h[1] = __float2half(ay * di);
    pk.h[2] = __float2half(az * di); pk.h[3] = __float2half(aw * di);
    *(uint2*)&At[nl * 72 + 4 * f4] = pk.u;    // feats 4*f4 .. 4*f4+3 of node nl
    if (f4 == 0) sDi[nl] = di;
    __syncthreads();

    // MFMA: D[m=node][n=col] = A(16x64) @ W2(64x64); this wave: cols 16*wid..
    half8 A0 = *reinterpret_cast<const half8*>(&At[m * 72 + quad * 8]);
    half8 A1 = *reinterpret_cast<const half8*>(&At[m * 72 + 32 + quad * 8]);
    float4v C = {0.f, 0.f, 0.f, 0.f};
    C = __builtin_amdgcn_mfma_f32_16x16x32_f16(A0, H0, C, 0, 0, 0);
    C = __builtin_amdgcn_mfma_f32_16x16x32_f16(A0, L0, C, 0, 0, 0);
    C = __builtin_amdgcn_mfma_f32_16x16x32_f16(A1, H1, C, 0, 0, 0);
    C = __builtin_amdgcn_mfma_f32_16x16x32_f16(A1, L1, C, 0, 0, 0);

    // epilogue: relu(C+b2)*wfc, reduce over cols -> per-node scalar
    float v0 = fmaxf(C[0] + bc, 0.f) * wf;
    float v1 = fmaxf(C[1] + bc, 0.f) * wf;
    float v2 = fmaxf(C[2] + bc, 0.f) * wf;
    float v3 = fmaxf(C[3] + bc, 0.f) * wf;
    #pragma unroll
    for (int o = 1; o < 16; o <<= 1) {
        v0 += __shfl_xor(v0, o, 64);
        v1 += __shfl_xor(v1, o, 64);
        v2 += __shfl_xor(v2, o, 64);
        v3 += __shfl_xor(v3, o, 64);
    }
    if (m == 0) {
        sRed[wid][quad * 4 + 0] = v0;
        sRed[wid][quad * 4 + 1] = v1;
        sRed[wid][quad * 4 + 2] = v2;
        sRed[wid][quad * 4 + 3] = v3;
    }
    __syncthreads();
    if (t < 16) {
        int ng = blockIdx.x * 16 + t;
        if (ng < N) {
            float tt = sRed[0][t] + sRed[1][t] + sRed[2][t] + sRed[3][t];
            tvec[ng] = sDi[t] * tt;            // t_j = dinv_j * (h2_j . wfc)
        }
    }
}

// ========== layer 3: scalar gather over tvec (200KB) + mean-pool ==========
__global__ void k_agg3(const float* __restrict__ tvec, const int* __restrict__ rowptr,
                       const unsigned short* __restrict__ col, const float* __restrict__ dinv,
                       double* __restrict__ pool, int N) {
    int tid = blockIdx.x * 256 + threadIdx.x;
    int node = tid >> 4, lane = tid & 15;
    if (node >= N) return;
    int s0 = rowptr[node], s1 = rowptr[node + 1];
    float s = 0.f;
    for (int e = s0 + lane; e < s1; e += 16) s += tvec[col[e]];
    #pragma unroll
    for (int o = 1; o < 16; o <<= 1) s += __shfl_xor(s, o, 64);
    if (lane == 0) {
        double contrib = (double)(dinv[node] * (tvec[node] + s));
        atomicAdd(&pool[node & 255], contrib);
    }
}

__global__ void k_final(const double* __restrict__ pool, const float* __restrict__ wfc,
                        const float* __restrict__ fcb, float* __restrict__ out, double invN) {
    __shared__ double s[256];
    int t = threadIdx.x;
    s[t] = pool[t];
    __syncthreads();
    for (int o = 128; o > 0; o >>= 1) {
        if (t < o) s[t] += s[t + o];
        __syncthreads();
    }
    if (t == 0) out[0] = (float)(s[0] * invN) + wfc[64] + fcb[0];
}

extern "C" void kernel_launch(void* const* d_in, const int* in_sizes, int n_in,
                              void* d_out, int out_size, void* d_ws, size_t ws_size,
                              hipStream_t stream) {
    const float* x   = (const float*)d_in[0];
    const int*   ei  = (const int*)d_in[1];
    const float* W1  = (const float*)d_in[2];
    const float* b1  = (const float*)d_in[3];
    const float* W2  = (const float*)d_in[4];
    const float* b2  = (const float*)d_in[5];
    const float* W3  = (const float*)d_in[6];
    const float* b3  = (const float*)d_in[7];
    const float* fcW = (const float*)d_in[8];
    const float* fcb = (const float*)d_in[9];

    const int N = in_sizes[0] / 10;
    const int E = in_sizes[1] / 2;
    const int* src = ei;
    const int* dst = ei + E;

    const int K   = (N + BS - 1) >> 7;         // buckets of 128 nodes (391)
    const int NB  = (E + CHUNK - 1) / CHUNK;   // chunks (391)
    const int NBS = NB | 1;                    // odd stride

    // ---- workspace carve-up (256B aligned) ----
    char* w = (char*)d_ws;
    size_t off = 0;
    auto alloc = [&](size_t bytes) -> void* {
        void* p = w + off;
        off += (bytes + 255) & ~(size_t)255;
        return p;
    };
    int*      histT      = (int*)alloc((size_t)K * NBS * 4);
    int*      histP      = (int*)alloc((size_t)K * NBS * 4);
    int*      bucketBase = (int*)alloc((size_t)K * 4);
    int*      bucketCnt  = (int*)alloc((size_t)K * 4);
    unsigned* pairs      = (unsigned*)alloc((size_t)E * 4);
    unsigned short* col  = (unsigned short*)alloc((size_t)E * 2);
    int*      rowptr     = (int*)alloc((size_t)(N + 1) * 4);
    float*    dinv       = (float*)alloc((size_t)N * 4);
    double*   pool       = (double*)alloc(256 * 8);
    float*    wfc        = (float*)alloc(65 * 4);
    float*    tvec       = (float*)alloc((size_t)N * 4);
    __half*   gx         = (__half*)alloc((size_t)N * 16 * 2);
    __half*   g1         = (__half*)alloc((size_t)N * 64 * 2);   // interleaved h1, 128B/node
    (void)ws_size; (void)n_in; (void)out_size;

    const int nbNode16 = (N + 15) / 16;

    // ---- atomic-free CSR build (counting sort, LDS atomics only) ----
    k_hist   <<<NB, 1024, 0, stream>>>(dst, E, histT, histP, K, NBS,
                                       W3, fcW, b3, wfc, pool, rowptr, N);
    k_offsets<<<K, 256, 0, stream>>>(histT, histP, NB, NBS, K, bucketBase, bucketCnt);
    k_scatter<<<NB, 1024, 0, stream>>>(src, dst, E, histT, K, NBS, pairs);
    k_bucket <<<K, 1024, 0, stream>>>(pairs, bucketBase, bucketCnt, x,
                                      rowptr, dinv, gx, col, N);

    // ---- fused layers ----
    k_L1 <<<nbNode16, 256, 0, stream>>>(gx, W1, b1, rowptr, col, dinv, g1, N);
    k_L2 <<<nbNode16, 256, 0, stream>>>(g1, W2, b2, wfc, rowptr, col, dinv, tvec, N);
    k_agg3<<<nbNode16, 256, 0, stream>>>(tvec, rowptr, col, dinv, pool, N);
    k_final<<<1, 256, 0, stream>>>(pool, wfc, fcb, (float*)d_out, 1.0 / (double)N);
}

// Round 8
// 150.871 us; speedup vs baseline: 1.6199x; 1.0342x over previous
//
#include <hip/hip_runtime.h>
#include <hip/hip_fp16.h>

typedef _Float16 half8 __attribute__((ext_vector_type(8)));
typedef float float4v __attribute__((ext_vector_type(4)));

#define CHUNK 2048           // edges per scatter block
#define BS    128            // nodes per bucket
#define ARENA 6144           // arena capacity per bucket (mean cnt ~2046)
#define BCAP  6144           // LDS staging capacity in k_bucket

// ========== init: zero counters/pool + wfc = W3@fcW (1 block) ==========
__global__ void __launch_bounds__(1024) k_init(
        int* __restrict__ gcur, int* __restrict__ spillCnt,
        double* __restrict__ pool,
        const float* __restrict__ W3, const float* __restrict__ fcW,
        const float* __restrict__ b3, float* __restrict__ wfc) {
    int t = threadIdx.x;
    if (t < 512) gcur[t] = 0;
    if (t == 0) spillCnt[0] = 0;
    if (t >= 512 && t < 768) pool[t - 512] = 0.0;
    if (t < 64) {                                // wfc[c]=(W3@fcW)[c]; wfc[64]=b3.fcW
        float v = 0.f;
        #pragma unroll 8
        for (int j = 0; j < 64; ++j) v += W3[t * 64 + j] * fcW[j];
        wfc[t] = v;
        float bb = b3[t] * fcW[t];
        for (int o = 32; o > 0; o >>= 1) bb += __shfl_down(bb, o, 64);
        if (t == 0) wfc[64] = bb;
    }
}

// ========== single-pass scatter into fixed arenas (1024 thr, edges in regs) ==========
__global__ void __launch_bounds__(1024) k_scatter1(
        const int* __restrict__ src, const int* __restrict__ dst, int E,
        unsigned* __restrict__ pairs, int* __restrict__ gcur,
        unsigned* __restrict__ spill, int* __restrict__ spillCnt) {
    __shared__ int lh[512];      // hist, then per-bucket ticket counter
    __shared__ int gstart[512];  // this block's reserved range start per bucket
    int t = threadIdx.x, b = blockIdx.x;
    if (t < 512) lh[t] = 0;
    __syncthreads();
    int e0 = b * CHUNK + t, e1 = e0 + 1024;
    bool v0 = e0 < E, v1 = e1 < E;
    int d0 = 0, s0 = 0, d1 = 0, s1 = 0;
    if (v0) { d0 = dst[e0]; s0 = src[e0]; atomicAdd(&lh[d0 >> 7], 1); }
    if (v1) { d1 = dst[e1]; s1 = src[e1]; atomicAdd(&lh[d1 >> 7], 1); }
    __syncthreads();
    if (t < 512) {
        int c = lh[t];
        gstart[t] = c ? atomicAdd(&gcur[t], c) : 0;   // reserve arena range
    }
    __syncthreads();
    if (t < 512) lh[t] = 0;                           // reuse as ticket counter
    __syncthreads();
    if (v0) {
        int k = d0 >> 7;
        int pos = gstart[k] + atomicAdd(&lh[k], 1);
        unsigned pk = ((unsigned)(d0 & 127) << 16) | (unsigned)s0;
        if (pos < ARENA) pairs[k * ARENA + pos] = pk;
        else { int sp = atomicAdd(spillCnt, 1); spill[sp] = ((unsigned)k << 23) | pk; }
    }
    if (v1) {
        int k = d1 >> 7;
        int pos = gstart[k] + atomicAdd(&lh[k], 1);
        unsigned pk = ((unsigned)(d1 & 127) << 16) | (unsigned)s1;
        if (pos < ARENA) pairs[k * ARENA + pos] = pk;
        else { int sp = atomicAdd(spillCnt, 1); spill[sp] = ((unsigned)k << 23) | pk; }
    }
}

// ========== per-bucket exact CSR + rowbeg/deg/dinv/gx (1024 thr, 128-node bucket) ==========
__global__ void __launch_bounds__(1024) k_bucket(
        const unsigned* __restrict__ pairs, const int* __restrict__ gcur,
        const unsigned* __restrict__ spill, const int* __restrict__ spillCnt,
        const float* __restrict__ x,
        int* __restrict__ rowbeg, int* __restrict__ degv, float* __restrict__ dinv,
        __half* __restrict__ gx, unsigned short* __restrict__ col, int N) {
    __shared__ unsigned pl[BCAP];
    __shared__ unsigned short scol[BCAP];
    __shared__ int h[BS], nb[BS], cur[BS];
    __shared__ float sdi[BS];
    int k = blockIdx.x, t = threadIdx.x;
    int base = k * ARENA;
    int cnt = gcur[k];
    int cntA = cnt < ARENA ? cnt : ARENA;             // arena-resident entries
    int spN = spillCnt[0];
    bool stg = cntA <= BCAP;
    if (t < BS) h[t] = 0;
    if (stg) for (int i = t; i < cntA; i += 1024) pl[i] = pairs[base + i];
    __syncthreads();
    for (int i = t; i < cntA; i += 1024) {
        unsigned p = stg ? pl[i] : pairs[base + i];
        atomicAdd(&h[p >> 16], 1);                    // LDS atomic
    }
    for (int i = t; i < spN; i += 1024) {             // spill (normally 0)
        unsigned sp = spill[i];
        if ((int)(sp >> 23) == k) atomicAdd(&h[(sp >> 16) & 127], 1);
    }
    __syncthreads();
    int d = (t < BS) ? h[t] : 0;
    if (t < BS) nb[t] = d;
    __syncthreads();
    for (int o = 1; o < BS; o <<= 1) {
        int v = (t < BS && t >= o) ? nb[t - o] : 0;
        __syncthreads();
        if (t < BS) nb[t] += v;
        __syncthreads();
    }
    if (t < BS) {
        int excl = nb[t] - d;
        cur[t] = excl;
        int gid = (k << 7) + t;
        if (gid < N) {
            rowbeg[gid] = base + excl;
            degv[gid] = d;
            float di = rsqrtf((float)(d + 1));        // +1 self loop
            dinv[gid] = di;
            sdi[t] = di;
        }
    }
    __syncthreads();
    // gx fill: BS nodes x 16 halfs, spread across all 1024 threads
    for (int i = t; i < BS * 16; i += 1024) {
        int nl = i >> 4, q2 = i & 15;
        int gid = (k << 7) + nl;
        if (gid < N)
            gx[(unsigned)gid * 16 + q2] =
                __float2half(q2 < 10 ? x[gid * 10 + q2] * sdi[nl] : 0.f);
    }
    // placement: scatter into LDS, then stream out coalesced
    for (int i = t; i < cntA; i += 1024) {
        unsigned p = stg ? pl[i] : pairs[base + i];
        int j = p >> 16;
        int pos = atomicAdd(&cur[j], 1);              // LDS atomic
        if (stg) scol[pos] = (unsigned short)(p & 0xFFFFu);
        else if (pos < ARENA) col[base + pos] = (unsigned short)(p & 0xFFFFu);
    }
    for (int i = t; i < spN; i += 1024) {             // spill placement (normally 0)
        unsigned sp = spill[i];
        if ((int)(sp >> 23) == k) {
            int j = (sp >> 16) & 127;
            int pos = atomicAdd(&cur[j], 1);
            if (stg && pos < BCAP) scol[pos] = (unsigned short)(sp & 0xFFFFu);
            else if (pos < ARENA) col[base + pos] = (unsigned short)(sp & 0xFFFFu);
        }
    }
    __syncthreads();
    if (stg) {
        int tot = cnt < BCAP ? cnt : BCAP;
        for (int i = t; i < tot; i += 1024) col[base + i] = scol[i];
    }
}

// ========== layer 1: gather gx16 (1.6MB, L2-resident), 16 lanes/node ==========
// output: interleaved g1 (128B/node): lane f's 4 output feats at byte offset f*8
__global__ void k_L1(const __half* __restrict__ gx, const float* __restrict__ W1,
                     const float* __restrict__ b1, const int* __restrict__ rowbeg,
                     const int* __restrict__ degv,
                     const unsigned short* __restrict__ col, const float* __restrict__ dinv,
                     __half* __restrict__ g1, int N) {
    __shared__ float sW[10 * 64];
    __shared__ float sB[64];
    int t = threadIdx.x;
    for (int i = t; i < 640; i += 256) sW[i] = W1[i];
    if (t < 64) sB[t] = b1[t];
    __syncthreads();
    int node = blockIdx.x * 16 + (t >> 4);
    int f = t & 15;
    bool live = node < N;
    bool act = live && (f < 10);
    const char* gp = (const char*)gx;
    unsigned fo = (unsigned)(f << 1);
    float di = live ? dinv[node] : 0.f;
    float a = act ? __half2float(*(const __half*)(gp + ((unsigned)node << 5) + fo)) : 0.f;
    int s0 = 0, s1 = 0;
    if (live) { s0 = rowbeg[node]; s1 = s0 + degv[node]; }
    int e = s0;
    for (; e + 4 <= s1; e += 4) {
        unsigned j0 = col[e], j1 = col[e + 1], j2 = col[e + 2], j3 = col[e + 3];
        float v0 = 0.f, v1 = 0.f, v2 = 0.f, v3 = 0.f;
        if (act) {
            v0 = __half2float(*(const __half*)(gp + (j0 << 5) + fo));
            v1 = __half2float(*(const __half*)(gp + (j1 << 5) + fo));
            v2 = __half2float(*(const __half*)(gp + (j2 << 5) + fo));
            v3 = __half2float(*(const __half*)(gp + (j3 << 5) + fo));
        }
        a += (v0 + v1) + (v2 + v3);
    }
    for (; e < s1; ++e) {
        unsigned j = col[e];
        if (act) a += __half2float(*(const __half*)(gp + (j << 5) + fo));
    }
    a *= di;                                   // P_i(x)[f], f<10
    int gb = t & 48;
    float c0 = 0.f, c1 = 0.f, c2 = 0.f, c3 = 0.f;
    int c4 = 4 * f;
    #pragma unroll
    for (int k = 0; k < 10; ++k) {
        float ak = __shfl(a, gb + k, 64);
        c0 += ak * sW[k * 64 + c4];
        c1 += ak * sW[k * 64 + c4 + 1];
        c2 += ak * sW[k * 64 + c4 + 2];
        c3 += ak * sW[k * 64 + c4 + 3];
    }
    if (!live) return;
    float h0 = di * fmaxf(c0 + sB[c4], 0.f);
    float h1 = di * fmaxf(c1 + sB[c4 + 1], 0.f);
    float h2 = di * fmaxf(c2 + sB[c4 + 2], 0.f);
    float h3 = di * fmaxf(c3 + sB[c4 + 3], 0.f);
    union { __half h[4]; uint2 u; } pk;
    pk.h[0] = __float2half(h0); pk.h[1] = __float2half(h1);
    pk.h[2] = __float2half(h2); pk.h[3] = __float2half(h3);
    *(uint2*)((char*)g1 + ((unsigned)node << 7) + (unsigned)(f << 3)) = pk.u;
}

// ========== layer 2 (merged): single gather over g1 (6.4MB) + MFMA epilogue -> tvec ==========
__global__ void __launch_bounds__(256) k_L2(
        const __half* __restrict__ g1,
        const float* __restrict__ W2, const float* __restrict__ b2,
        const float* __restrict__ wfcv, const int* __restrict__ rowbeg,
        const int* __restrict__ degv,
        const unsigned short* __restrict__ col, const float* __restrict__ dinv,
        float* __restrict__ tvec, int N) {
    __shared__ __align__(16) __half At[16 * 72];   // 16 nodes x 64 feats, stride 72
    __shared__ float sRed[4][16];
    __shared__ float sDi[16];
    int t = threadIdx.x;
    int lane = t & 63, wid = t >> 6;
    int m = lane & 15, quad = lane >> 4;

    // B fragments: W2 column cg, fp16 hi/lo split (registers, overlaps gather)
    int cg = (wid << 4) + m;
    half8 H0, L0, H1, L1;
    #pragma unroll
    for (int j = 0; j < 8; ++j) {
        float w0 = W2[(quad * 8 + j) * 64 + cg];
        _Float16 h0 = (_Float16)w0;
        H0[j] = h0; L0[j] = (_Float16)(w0 - (float)h0);
        float w1 = W2[(32 + quad * 8 + j) * 64 + cg];
        _Float16 h1 = (_Float16)w1;
        H1[j] = h1; L1[j] = (_Float16)(w1 - (float)h1);
    }
    float bc = b2[cg], wf = wfcv[cg];

    // gather g1: 16 nodes/block, 16 lanes/node, 4 feats (uint2, 8B) per lane
    int nl = t >> 4, f4 = t & 15;
    int node = blockIdx.x * 16 + nl;
    bool live = node < N;
    float di = live ? dinv[node] : 0.f;
    float ax = 0.f, ay = 0.f, az = 0.f, aw = 0.f;
    if (live) {
        const char* gp = (const char*)g1;
        unsigned fo = (unsigned)(f4 << 3);
        uint2 us = *(const uint2*)(gp + ((unsigned)node << 7) + fo);
        float2 slo = __half22float2(*(__half2*)&us.x);
        float2 shi = __half22float2(*(__half2*)&us.y);
        ax = slo.x; ay = slo.y; az = shi.x; aw = shi.y;
        int s0 = rowbeg[node], s1 = s0 + degv[node];
        int e = s0;
        for (; e + 8 <= s1; e += 8) {
            unsigned j0 = col[e],     j1 = col[e + 1], j2 = col[e + 2], j3 = col[e + 3];
            unsigned j4 = col[e + 4], j5 = col[e + 5], j6 = col[e + 6], j7 = col[e + 7];
            uint2 u0 = *(const uint2*)(gp + (j0 << 7) + fo);
            uint2 u1 = *(const uint2*)(gp + (j1 << 7) + fo);
            uint2 u2 = *(const uint2*)(gp + (j2 << 7) + fo);
            uint2 u3 = *(const uint2*)(gp + (j3 << 7) + fo);
            uint2 u4 = *(const uint2*)(gp + (j4 << 7) + fo);
            uint2 u5 = *(const uint2*)(gp + (j5 << 7) + fo);
            uint2 u6 = *(const uint2*)(gp + (j6 << 7) + fo);
            uint2 u7 = *(const uint2*)(gp + (j7 << 7) + fo);
            float2 a0 = __half22float2(*(__half2*)&u0.x), b0 = __half22float2(*(__half2*)&u0.y);
            float2 a1 = __half22float2(*(__half2*)&u1.x), b1v = __half22float2(*(__half2*)&u1.y);
            float2 a2 = __half22float2(*(__half2*)&u2.x), b2v = __half22float2(*(__half2*)&u2.y);
            float2 a3 = __half22float2(*(__half2*)&u3.x), b3v = __half22float2(*(__half2*)&u3.y);
            float2 a4 = __half22float2(*(__half2*)&u4.x), b4 = __half22float2(*(__half2*)&u4.y);
            float2 a5 = __half22float2(*(__half2*)&u5.x), b5 = __half22float2(*(__half2*)&u5.y);
            float2 a6 = __half22float2(*(__half2*)&u6.x), b6 = __half22float2(*(__half2*)&u6.y);
            float2 a7 = __half22float2(*(__half2*)&u7.x), b7 = __half22float2(*(__half2*)&u7.y);
            ax += ((a0.x + a1.x) + (a2.x + a3.x)) + ((a4.x + a5.x) + (a6.x + a7.x));
            ay += ((a0.y + a1.y) + (a2.y + a3.y)) + ((a4.y + a5.y) + (a6.y + a7.y));
            az += ((b0.x + b1v.x) + (b2v.x + b3v.x)) + ((b4.x + b5.x) + (b6.x + b7.x));
            aw += ((b0.y + b1v.y) + (b2v.y + b3v.y)) + ((b4.y + b5.y) + (b6.y + b7.y));
        }
        for (; e < s1; ++e) {
            uint2 u0 = *(const uint2*)(gp + ((unsigned)col[e] << 7) + fo);
            float2 a0 = __half22float2(*(__half2*)&u0.x), b0 = __half22float2(*(__half2*)&u0.y);
            ax += a0.x; ay += a0.y; az += b0.x; aw += b0.y;
        }
    }
    union { __half h[4]; uint2 u; } pk;
    pk.h[0] = __float2half(ax * di); pk.h[1] = __float2half(ay * di);
    pk.h[2] = __float2half(az * di); pk.h[3] = __float2half(aw * di);
    *(uint2*)&At[nl * 72 + 4 * f4] = pk.u;    // feats 4*f4 .. 4*f4+3 of node nl
    if (f4 == 0) sDi[nl] = di;
    __syncthreads();

    // MFMA: D[m=node][n=col] = A(16x64) @ W2(64x64); this wave: cols 16*wid..
    half8 A0 = *reinterpret_cast<const half8*>(&At[m * 72 + quad * 8]);
    half8 A1 = *reinterpret_cast<const half8*>(&At[m * 72 + 32 + quad * 8]);
    float4v C = {0.f, 0.f, 0.f, 0.f};
    C = __builtin_amdgcn_mfma_f32_16x16x32_f16(A0, H0, C, 0, 0, 0);
    C = __builtin_amdgcn_mfma_f32_16x16x32_f16(A0, L0, C, 0, 0, 0);
    C = __builtin_amdgcn_mfma_f32_16x16x32_f16(A1, H1, C, 0, 0, 0);
    C = __builtin_amdgcn_mfma_f32_16x16x32_f16(A1, L1, C, 0, 0, 0);

    // epilogue: relu(C+b2)*wfc, reduce over cols -> per-node scalar
    float v0 = fmaxf(C[0] + bc, 0.f) * wf;
    float v1 = fmaxf(C[1] + bc, 0.f) * wf;
    float v2 = fmaxf(C[2] + bc, 0.f) * wf;
    float v3 = fmaxf(C[3] + bc, 0.f) * wf;
    #pragma unroll
    for (int o = 1; o < 16; o <<= 1) {
        v0 += __shfl_xor(v0, o, 64);
        v1 += __shfl_xor(v1, o, 64);
        v2 += __shfl_xor(v2, o, 64);
        v3 += __shfl_xor(v3, o, 64);
    }
    if (m == 0) {
        sRed[wid][quad * 4 + 0] = v0;
        sRed[wid][quad * 4 + 1] = v1;
        sRed[wid][quad * 4 + 2] = v2;
        sRed[wid][quad * 4 + 3] = v3;
    }
    __syncthreads();
    if (t < 16) {
        int ng = blockIdx.x * 16 + t;
        if (ng < N) {
            float tt = sRed[0][t] + sRed[1][t] + sRed[2][t] + sRed[3][t];
            tvec[ng] = sDi[t] * tt;            // t_j = dinv_j * (h2_j . wfc)
        }
    }
}

// ========== layer 3: scalar gather over tvec (200KB) + mean-pool ==========
__global__ void k_agg3(const float* __restrict__ tvec, const int* __restrict__ rowbeg,
                       const int* __restrict__ degv,
                       const unsigned short* __restrict__ col, const float* __restrict__ dinv,
                       double* __restrict__ pool, int N) {
    int tid = blockIdx.x * 256 + threadIdx.x;
    int node = tid >> 4, lane = tid & 15;
    if (node >= N) return;
    int s0 = rowbeg[node], s1 = s0 + degv[node];
    float s = 0.f;
    for (int e = s0 + lane; e < s1; e += 16) s += tvec[col[e]];
    #pragma unroll
    for (int o = 1; o < 16; o <<= 1) s += __shfl_xor(s, o, 64);
    if (lane == 0) {
        double contrib = (double)(dinv[node] * (tvec[node] + s));
        atomicAdd(&pool[node & 255], contrib);
    }
}

__global__ void k_final(const double* __restrict__ pool, const float* __restrict__ wfc,
                        const float* __restrict__ fcb, float* __restrict__ out, double invN) {
    __shared__ double s[256];
    int t = threadIdx.x;
    s[t] = pool[t];
    __syncthreads();
    for (int o = 128; o > 0; o >>= 1) {
        if (t < o) s[t] += s[t + o];
        __syncthreads();
    }
    if (t == 0) out[0] = (float)(s[0] * invN) + wfc[64] + fcb[0];
}

extern "C" void kernel_launch(void* const* d_in, const int* in_sizes, int n_in,
                              void* d_out, int out_size, void* d_ws, size_t ws_size,
                              hipStream_t stream) {
    const float* x   = (const float*)d_in[0];
    const int*   ei  = (const int*)d_in[1];
    const float* W1  = (const float*)d_in[2];
    const float* b1  = (const float*)d_in[3];
    const float* W2  = (const float*)d_in[4];
    const float* b2  = (const float*)d_in[5];
    const float* W3  = (const float*)d_in[6];
    const float* b3  = (const float*)d_in[7];
    const float* fcW = (const float*)d_in[8];
    const float* fcb = (const float*)d_in[9];

    const int N = in_sizes[0] / 10;
    const int E = in_sizes[1] / 2;
    const int* src = ei;
    const int* dst = ei + E;

    const int K   = (N + BS - 1) >> 7;         // buckets of 128 nodes (391)
    const int NB  = (E + CHUNK - 1) / CHUNK;   // scatter chunks (391)

    // ---- workspace carve-up (256B aligned) ----
    char* w = (char*)d_ws;
    size_t off = 0;
    auto alloc = [&](size_t bytes) -> void* {
        void* p = w + off;
        off += (bytes + 255) & ~(size_t)255;
        return p;
    };
    int*      gcur       = (int*)alloc(512 * 4);
    int*      spillCnt   = (int*)alloc(256);
    unsigned* spill      = (unsigned*)alloc((size_t)E * 4);
    unsigned* pairs      = (unsigned*)alloc((size_t)K * ARENA * 4);
    unsigned short* col  = (unsigned short*)alloc((size_t)K * ARENA * 2);
    int*      rowbeg     = (int*)alloc((size_t)N * 4);
    int*      degv       = (int*)alloc((size_t)N * 4);
    float*    dinv       = (float*)alloc((size_t)N * 4);
    double*   pool       = (double*)alloc(256 * 8);
    float*    wfc        = (float*)alloc(65 * 4);
    float*    tvec       = (float*)alloc((size_t)N * 4);
    __half*   gx         = (__half*)alloc((size_t)N * 16 * 2);
    __half*   g1         = (__half*)alloc((size_t)N * 64 * 2);   // interleaved h1, 128B/node
    (void)ws_size; (void)n_in; (void)out_size;

    const int nbNode16 = (N + 15) / 16;

    // ---- single-pass arena CSR build ----
    k_init    <<<1, 1024, 0, stream>>>(gcur, spillCnt, pool, W3, fcW, b3, wfc);
    k_scatter1<<<NB, 1024, 0, stream>>>(src, dst, E, pairs, gcur, spill, spillCnt);
    k_bucket  <<<K, 1024, 0, stream>>>(pairs, gcur, spill, spillCnt, x,
                                       rowbeg, degv, dinv, gx, col, N);

    // ---- fused layers ----
    k_L1 <<<nbNode16, 256, 0, stream>>>(gx, W1, b1, rowbeg, degv, col, dinv, g1, N);
    k_L2 <<<nbNode16, 256, 0, stream>>>(g1, W2, b2, wfc, rowbeg, degv, col, dinv, tvec, N);
    k_agg3<<<nbNode16, 256, 0, stream>>>(tvec, rowbeg, degv, col, dinv, pool, N);
    k_final<<<1, 256, 0, stream>>>(pool, wfc, fcb, (float*)d_out, 1.0 / (double)N);
}